// Round 1
// baseline (6328.866 us; speedup 1.0000x reference)
//
#include <hip/hip_runtime.h>

// ---------------------------------------------------------------------------
// KAN-GNN forward on MI355X.  Sizes (fixed by reference): N=100000 nodes,
// E=1600000 edges, IN=64, MID=5, HID=128, OUT=1, NG=512 graphs, C=11 basis.
// ---------------------------------------------------------------------------

#define IN_F   64
#define MID_F  5
#define HID_F  128
#define NG     512
#define NC     11   // G_GRID + K_SPLINE = 8 + 3

// Cubic B-spline basis on uniform knots t_j = -1.75 + 0.25 j, j=0..14.
// Replicates the reference Cox-de Boor recursion (half-open deg-0 intervals,
// so x outside [-1.75, 1.75) -> all-zero basis).
__device__ __forceinline__ void bspline11(float x, float* __restrict__ B) {
    float b[14];
#pragma unroll
    for (int j = 0; j < 14; ++j) {
        float tj = -1.75f + 0.25f * j;
        b[j] = (x >= tj && x < tj + 0.25f) ? 1.0f : 0.0f;
    }
#pragma unroll
    for (int d = 1; d <= 3; ++d) {
        float inv = 1.0f / (0.25f * d);
#pragma unroll 14
        for (int j = 0; j < 14 - 3; ++j) {   // only first 11 needed at the end
            if (j < 14 - d) {
                float tj   = -1.75f + 0.25f * j;
                float tjd1 = tj + 0.25f * (d + 1);
                b[j] = ((x - tj) * b[j] + (tjd1 - x) * b[j + 1]) * inv;
            }
        }
        // elements 11..13-d also needed while recursing
        if (d < 3) {
#pragma unroll
            for (int j = 11; j < 14; ++j) {
                if (j < 14 - d) {
                    float tj   = -1.75f + 0.25f * j;
                    float tjd1 = tj + 0.25f * (d + 1);
                    b[j] = ((x - tj) * b[j] + (tjd1 - x) * b[j + 1]) * inv;
                }
            }
        }
    }
#pragma unroll
    for (int j = 0; j < NC; ++j) B[j] = b[j];
}

__device__ __forceinline__ float silu_f(float x) { return x / (1.0f + expf(-x)); }

// -------------------- KAN encoder layer 1: [N,64] -> [N,5] -----------------
__global__ __launch_bounds__(256) void enc1_kernel(
    const float* __restrict__ h, const float* __restrict__ coef1,
    const float* __restrict__ sb1, const float* __restrict__ ss1,
    float* __restrict__ mid, int N)
{
    __shared__ float s_coef[IN_F * MID_F * NC];  // coef1 * ss1 folded
    __shared__ float s_sb[IN_F * MID_F];
    for (int idx = threadIdx.x; idx < IN_F * MID_F * NC; idx += 256)
        s_coef[idx] = coef1[idx] * ss1[idx / NC];
    for (int idx = threadIdx.x; idx < IN_F * MID_F; idx += 256)
        s_sb[idx] = sb1[idx];
    __syncthreads();

    int n = blockIdx.x * 256 + threadIdx.x;
    if (n >= N) return;
    float acc[MID_F] = {0, 0, 0, 0, 0};
    const float* hr = h + (size_t)n * IN_F;
    for (int i = 0; i < IN_F; ++i) {
        float x = hr[i];
        float B[NC];
        bspline11(x, B);
        float s = silu_f(x);
        const float* cp = s_coef + i * (MID_F * NC);
        const float* sp = s_sb + i * MID_F;
#pragma unroll
        for (int o = 0; o < MID_F; ++o) {
            float t = 0.f;
#pragma unroll
            for (int c = 0; c < NC; ++c) t = fmaf(cp[o * NC + c], B[c], t);
            acc[o] += sp[o] * s + t;
        }
    }
#pragma unroll
    for (int o = 0; o < MID_F; ++o) mid[(size_t)n * MID_F + o] = acc[o];
}

// -------------------- KAN encoder layer 2: [N,5] -> [N,128] ----------------
__global__ __launch_bounds__(256) void enc2_kernel(
    const float* __restrict__ mid, const float* __restrict__ coef2,
    const float* __restrict__ sb2, const float* __restrict__ ss2,
    float* __restrict__ h0, int N)
{
    __shared__ float s_coef[MID_F * HID_F * NC];  // 7040 floats
    __shared__ float s_sb[MID_F * HID_F];
    __shared__ float s_B[2][MID_F][NC];
    __shared__ float s_sil[2][MID_F];
    for (int idx = threadIdx.x; idx < MID_F * HID_F * NC; idx += 256)
        s_coef[idx] = coef2[idx] * ss2[idx / NC];
    for (int idx = threadIdx.x; idx < MID_F * HID_F; idx += 256)
        s_sb[idx] = sb2[idx];

    int nTiles = (N + 1) / 2;
    for (int tile = blockIdx.x; tile < nTiles; tile += gridDim.x) {
        __syncthreads();  // coef ready (1st iter) / previous reads done
        int ln = threadIdx.x >> 7;
        int o  = threadIdx.x & 127;
        int n  = tile * 2 + ln;
        if (o < MID_F && n < N) {
            float x = mid[(size_t)n * MID_F + o];
            bspline11(x, &s_B[ln][o][0]);
            s_sil[ln][o] = silu_f(x);
        }
        __syncthreads();
        if (n < N) {
            float z = 0.f;
#pragma unroll
            for (int i = 0; i < MID_F; ++i) {
                const float* cp = s_coef + (i * HID_F + o) * NC;
                float t = 0.f;
#pragma unroll
                for (int c = 0; c < NC; ++c) t = fmaf(cp[c], s_B[ln][i][c], t);
                z += s_sb[i * HID_F + o] * s_sil[ln][i] + t;
            }
            h0[(size_t)n * HID_F + o] = z;
        }
    }
}

// -------------------- degree --------------------
__global__ void deg_kernel(const int* __restrict__ dst, float* __restrict__ deg, int E) {
    int e = blockIdx.x * 256 + threadIdx.x;
    if (e < E) atomicAdd(&deg[dst[e]], 1.0f);
}

// -------------------- edge scatter (sum of h[src] into acc[dst]) -----------
__global__ __launch_bounds__(256) void scatter_kernel(
    const float* __restrict__ hin, const int* __restrict__ src,
    const int* __restrict__ dst, float* __restrict__ acc, int E)
{
    int t = blockIdx.x * 256 + threadIdx.x;      // E*32 = 51.2M < 2^31
    if (t >= E * 32) return;
    int e = t >> 5;
    int c = t & 31;
    int s = src[e], d = dst[e];
    const float4 v = *(const float4*)(hin + (size_t)s * HID_F + c * 4);
    float* ap = acc + (size_t)d * HID_F + c * 4;
    atomicAdd(ap + 0, v.x);
    atomicAdd(ap + 1, v.y);
    atomicAdd(ap + 2, v.z);
    atomicAdd(ap + 3, v.w);
}

// -------------------- SAGE update: z = h@Ws + mean@Wn + b + h; leaky -------
__global__ __launch_bounds__(256) void sage_kernel(
    const float* __restrict__ hin, const float* __restrict__ acc,
    const float* __restrict__ deg, const float* __restrict__ Ws,
    const float* __restrict__ Wn, const float* __restrict__ bias,
    float* __restrict__ hout, int N)
{
    __shared__ float s_h[32][HID_F];
    __shared__ float s_m[32][HID_F];
    int n0 = blockIdx.x * 32;
    for (int idx = threadIdx.x; idx < 32 * HID_F; idx += 256) {
        int nl = idx >> 7, i = idx & 127;
        int n = n0 + nl;
        float hv = 0.f, mv = 0.f;
        if (n < N) {
            hv = hin[(size_t)n * HID_F + i];
            mv = acc[(size_t)n * HID_F + i] * (1.0f / fmaxf(deg[n], 1.0f));
        }
        s_h[nl][i] = hv;
        s_m[nl][i] = mv;
    }
    __syncthreads();
    int og = threadIdx.x & 31;   // output group: 4 consecutive outputs
    int ng = threadIdx.x >> 5;   // node group:   4 consecutive nodes
    int o0 = og * 4, nl0 = ng * 4;
    float z[4][4] = {};
#pragma unroll 4
    for (int i = 0; i < HID_F; ++i) {
        float4 wsv = *(const float4*)(Ws + i * HID_F + o0);
        float4 wnv = *(const float4*)(Wn + i * HID_F + o0);
#pragma unroll
        for (int a = 0; a < 4; ++a) {
            float hv = s_h[nl0 + a][i];
            float mv = s_m[nl0 + a][i];
            z[a][0] = fmaf(hv, wsv.x, fmaf(mv, wnv.x, z[a][0]));
            z[a][1] = fmaf(hv, wsv.y, fmaf(mv, wnv.y, z[a][1]));
            z[a][2] = fmaf(hv, wsv.z, fmaf(mv, wnv.z, z[a][2]));
            z[a][3] = fmaf(hv, wsv.w, fmaf(mv, wnv.w, z[a][3]));
        }
    }
    float4 bv = *(const float4*)(bias + o0);
#pragma unroll
    for (int a = 0; a < 4; ++a) {
        int n = n0 + nl0 + a;
        if (n >= N) break;
        float4 r;
        r.x = z[a][0] + bv.x + s_h[nl0 + a][o0 + 0];
        r.y = z[a][1] + bv.y + s_h[nl0 + a][o0 + 1];
        r.z = z[a][2] + bv.z + s_h[nl0 + a][o0 + 2];
        r.w = z[a][3] + bv.w + s_h[nl0 + a][o0 + 3];
        r.x = r.x > 0.f ? r.x : 0.01f * r.x;
        r.y = r.y > 0.f ? r.y : 0.01f * r.y;
        r.z = r.z > 0.f ? r.z : 0.01f * r.z;
        r.w = r.w > 0.f ? r.w : 0.01f * r.w;
        *(float4*)(hout + (size_t)n * HID_F + o0) = r;
    }
}

// -------------------- mean pool per graph (gid sorted -> binary search) ----
__global__ __launch_bounds__(128) void pool_kernel(
    const float* __restrict__ h, const int* __restrict__ gid,
    float* __restrict__ ybuf, int N)
{
    int g = blockIdx.x;
    __shared__ int s_lo, s_hi;
    if (threadIdx.x == 0) {
        int lo = 0, hi = N;
        while (lo < hi) { int m = (lo + hi) >> 1; if (gid[m] < g) lo = m + 1; else hi = m; }
        s_lo = lo;
        int lo2 = lo, hi2 = N;
        while (lo2 < hi2) { int m = (lo2 + hi2) >> 1; if (gid[m] < g + 1) lo2 = m + 1; else hi2 = m; }
        s_hi = lo2;
    }
    __syncthreads();
    int lo = s_lo, hi = s_hi;
    float inv = 1.0f / fmaxf((float)(hi - lo), 1.0f);
    int o = threadIdx.x;
    float acc = 0.f;
    for (int n = lo; n < hi; ++n) acc += h[(size_t)n * HID_F + o];
    ybuf[g * HID_F + o] = acc * inv;
}

// -------------------- KAN readout layer 1: [512,128] -> [512,5] ------------
__global__ __launch_bounds__(256) void readout1_kernel(
    const float* __restrict__ ybuf, const float* __restrict__ coefr1,
    const float* __restrict__ sbr1, const float* __restrict__ ssr1,
    float* __restrict__ ymid)
{
    __shared__ float s_coef[HID_F * MID_F * NC];
    __shared__ float s_sb[HID_F * MID_F];
    for (int idx = threadIdx.x; idx < HID_F * MID_F * NC; idx += 256)
        s_coef[idx] = coefr1[idx] * ssr1[idx / NC];
    for (int idx = threadIdx.x; idx < HID_F * MID_F; idx += 256)
        s_sb[idx] = sbr1[idx];
    __syncthreads();
    int g = blockIdx.x * 256 + threadIdx.x;
    if (g >= NG) return;
    float acc[MID_F] = {0, 0, 0, 0, 0};
    for (int i = 0; i < HID_F; ++i) {
        float x = ybuf[g * HID_F + i];
        float B[NC];
        bspline11(x, B);
        float s = silu_f(x);
        const float* cp = s_coef + i * (MID_F * NC);
#pragma unroll
        for (int o = 0; o < MID_F; ++o) {
            float t = 0.f;
#pragma unroll
            for (int c = 0; c < NC; ++c) t = fmaf(cp[o * NC + c], B[c], t);
            acc[o] += s_sb[i * MID_F + o] * s + t;
        }
    }
#pragma unroll
    for (int o = 0; o < MID_F; ++o) ymid[g * MID_F + o] = acc[o];
}

// -------------------- KAN readout layer 2 + sigmoid: [512,5] -> [512,1] ----
__global__ __launch_bounds__(256) void readout2_kernel(
    const float* __restrict__ ymid, const float* __restrict__ coefr2,
    const float* __restrict__ sbr2, const float* __restrict__ ssr2,
    float* __restrict__ out)
{
    int g = blockIdx.x * 256 + threadIdx.x;
    if (g >= NG) return;
    float acc = 0.f;
#pragma unroll
    for (int i = 0; i < MID_F; ++i) {
        float x = ymid[g * MID_F + i];
        float B[NC];
        bspline11(x, B);
        float t = 0.f;
#pragma unroll
        for (int c = 0; c < NC; ++c) t = fmaf(coefr2[i * NC + c], B[c], t);
        acc += sbr2[i] * silu_f(x) + ssr2[i] * t;
    }
    out[g] = 1.0f / (1.0f + expf(-acc));
}

// ---------------------------------------------------------------------------
extern "C" void kernel_launch(void* const* d_in, const int* in_sizes, int n_in,
                              void* d_out, int out_size, void* d_ws, size_t ws_size,
                              hipStream_t stream)
{
    const float* h     = (const float*)d_in[0];
    const int*   src   = (const int*)d_in[1];
    const int*   dst   = (const int*)d_in[2];
    const int*   gid   = (const int*)d_in[3];
    const float* coef1 = (const float*)d_in[4];
    const float* sb1   = (const float*)d_in[5];
    const float* ss1   = (const float*)d_in[6];
    const float* coef2 = (const float*)d_in[7];
    const float* sb2   = (const float*)d_in[8];
    const float* ss2   = (const float*)d_in[9];
    const float* Ws0   = (const float*)d_in[10];
    const float* Wn0   = (const float*)d_in[11];
    const float* b0    = (const float*)d_in[12];
    const float* Ws1   = (const float*)d_in[13];
    const float* Wn1   = (const float*)d_in[14];
    const float* b1    = (const float*)d_in[15];
    const float* coefr1= (const float*)d_in[16];
    const float* sbr1  = (const float*)d_in[17];
    const float* ssr1  = (const float*)d_in[18];
    const float* coefr2= (const float*)d_in[19];
    const float* sbr2  = (const float*)d_in[20];
    const float* ssr2  = (const float*)d_in[21];

    const int N = in_sizes[0] / IN_F;   // 100000
    const int E = in_sizes[1];          // 1600000

    float* ws   = (float*)d_ws;
    float* mid  = ws;                          // N*5
    float* deg  = mid + (size_t)N * MID_F;     // N
    float* h0   = deg + N;                     // N*128
    float* h1   = h0 + (size_t)N * HID_F;      // N*128
    float* acc  = h1 + (size_t)N * HID_F;      // N*128
    float* ybuf = acc + (size_t)N * HID_F;     // 512*128
    float* ymid = ybuf + NG * HID_F;           // 512*5

    hipMemsetAsync(deg, 0, (size_t)N * sizeof(float), stream);

    enc1_kernel<<<(N + 255) / 256, 256, 0, stream>>>(h, coef1, sb1, ss1, mid, N);
    enc2_kernel<<<2048, 256, 0, stream>>>(mid, coef2, sb2, ss2, h0, N);
    deg_kernel<<<(E + 255) / 256, 256, 0, stream>>>(dst, deg, E);

    // SAGE layer 0
    hipMemsetAsync(acc, 0, (size_t)N * HID_F * sizeof(float), stream);
    scatter_kernel<<<(E * 32 + 255) / 256, 256, 0, stream>>>(h0, src, dst, acc, E);
    sage_kernel<<<(N + 31) / 32, 256, 0, stream>>>(h0, acc, deg, Ws0, Wn0, b0, h1, N);

    // SAGE layer 1
    hipMemsetAsync(acc, 0, (size_t)N * HID_F * sizeof(float), stream);
    scatter_kernel<<<(E * 32 + 255) / 256, 256, 0, stream>>>(h1, src, dst, acc, E);
    sage_kernel<<<(N + 31) / 32, 256, 0, stream>>>(h1, acc, deg, Ws1, Wn1, b1, h0, N);

    pool_kernel<<<NG, 128, 0, stream>>>(h0, gid, ybuf, N);
    readout1_kernel<<<2, 256, 0, stream>>>(ybuf, coefr1, sbr1, ssr1, ymid);
    readout2_kernel<<<2, 256, 0, stream>>>(ymid, coefr2, sbr2, ssr2, (float*)d_out);
}

// Round 2
// 1177.398 us; speedup vs baseline: 5.3753x; 5.3753x over previous
//
#include <hip/hip_runtime.h>

// ---------------------------------------------------------------------------
// KAN-GNN forward on MI355X.  Sizes (fixed by reference): N=100000 nodes,
// E=1600000 edges, IN=64, MID=5, HID=128, OUT=1, NG=512 graphs, C=11 basis.
// Round 2: replace fp32-atomic scatter (2x2.7ms, 3.2GB atomic write traffic)
// with per-launch CSR build + wave-per-node gather aggregation.
// ---------------------------------------------------------------------------

#define IN_F   64
#define MID_F  5
#define HID_F  128
#define NG     512
#define NC     11   // G_GRID + K_SPLINE = 8 + 3

// Cubic B-spline basis on uniform knots t_j = -1.75 + 0.25 j, j=0..14.
__device__ __forceinline__ void bspline11(float x, float* __restrict__ B) {
    float b[14];
#pragma unroll
    for (int j = 0; j < 14; ++j) {
        float tj = -1.75f + 0.25f * j;
        b[j] = (x >= tj && x < tj + 0.25f) ? 1.0f : 0.0f;
    }
#pragma unroll
    for (int d = 1; d <= 3; ++d) {
        float inv = 1.0f / (0.25f * d);
#pragma unroll 14
        for (int j = 0; j < 14 - 3; ++j) {
            if (j < 14 - d) {
                float tj   = -1.75f + 0.25f * j;
                float tjd1 = tj + 0.25f * (d + 1);
                b[j] = ((x - tj) * b[j] + (tjd1 - x) * b[j + 1]) * inv;
            }
        }
        if (d < 3) {
#pragma unroll
            for (int j = 11; j < 14; ++j) {
                if (j < 14 - d) {
                    float tj   = -1.75f + 0.25f * j;
                    float tjd1 = tj + 0.25f * (d + 1);
                    b[j] = ((x - tj) * b[j] + (tjd1 - x) * b[j + 1]) * inv;
                }
            }
        }
    }
#pragma unroll
    for (int j = 0; j < NC; ++j) B[j] = b[j];
}

__device__ __forceinline__ float silu_f(float x) { return x / (1.0f + expf(-x)); }

// -------------------- KAN encoder layer 1: [N,64] -> [N,5] -----------------
__global__ __launch_bounds__(256) void enc1_kernel(
    const float* __restrict__ h, const float* __restrict__ coef1,
    const float* __restrict__ sb1, const float* __restrict__ ss1,
    float* __restrict__ mid, int N)
{
    __shared__ float s_coef[IN_F * MID_F * NC];
    __shared__ float s_sb[IN_F * MID_F];
    for (int idx = threadIdx.x; idx < IN_F * MID_F * NC; idx += 256)
        s_coef[idx] = coef1[idx] * ss1[idx / NC];
    for (int idx = threadIdx.x; idx < IN_F * MID_F; idx += 256)
        s_sb[idx] = sb1[idx];
    __syncthreads();

    int n = blockIdx.x * 256 + threadIdx.x;
    if (n >= N) return;
    float acc[MID_F] = {0, 0, 0, 0, 0};
    const float* hr = h + (size_t)n * IN_F;
    for (int i = 0; i < IN_F; ++i) {
        float x = hr[i];
        float B[NC];
        bspline11(x, B);
        float s = silu_f(x);
        const float* cp = s_coef + i * (MID_F * NC);
        const float* sp = s_sb + i * MID_F;
#pragma unroll
        for (int o = 0; o < MID_F; ++o) {
            float t = 0.f;
#pragma unroll
            for (int c = 0; c < NC; ++c) t = fmaf(cp[o * NC + c], B[c], t);
            acc[o] += sp[o] * s + t;
        }
    }
#pragma unroll
    for (int o = 0; o < MID_F; ++o) mid[(size_t)n * MID_F + o] = acc[o];
}

// -------------------- KAN encoder layer 2: [N,5] -> [N,128] ----------------
__global__ __launch_bounds__(256) void enc2_kernel(
    const float* __restrict__ mid, const float* __restrict__ coef2,
    const float* __restrict__ sb2, const float* __restrict__ ss2,
    float* __restrict__ h0, int N)
{
    __shared__ float s_coef[MID_F * HID_F * NC];  // 7040 floats
    __shared__ float s_sb[MID_F * HID_F];
    __shared__ float s_B[2][MID_F][NC];
    __shared__ float s_sil[2][MID_F];
    for (int idx = threadIdx.x; idx < MID_F * HID_F * NC; idx += 256)
        s_coef[idx] = coef2[idx] * ss2[idx / NC];
    for (int idx = threadIdx.x; idx < MID_F * HID_F; idx += 256)
        s_sb[idx] = sb2[idx];

    int nTiles = (N + 1) / 2;
    for (int tile = blockIdx.x; tile < nTiles; tile += gridDim.x) {
        __syncthreads();
        int ln = threadIdx.x >> 7;
        int o  = threadIdx.x & 127;
        int n  = tile * 2 + ln;
        if (o < MID_F && n < N) {
            float x = mid[(size_t)n * MID_F + o];
            bspline11(x, &s_B[ln][o][0]);
            s_sil[ln][o] = silu_f(x);
        }
        __syncthreads();
        if (n < N) {
            float z = 0.f;
#pragma unroll
            for (int i = 0; i < MID_F; ++i) {
                const float* cp = s_coef + (i * HID_F + o) * NC;
                float t = 0.f;
#pragma unroll
                for (int c = 0; c < NC; ++c) t = fmaf(cp[c], s_B[ln][i][c], t);
                z += s_sb[i * HID_F + o] * s_sil[ln][i] + t;
            }
            h0[(size_t)n * HID_F + o] = z;
        }
    }
}

// -------------------- CSR build: count / scan / fill -----------------------
__global__ __launch_bounds__(256) void count_kernel(
    const int* __restrict__ dst, int* __restrict__ cnt, int E)
{
    int e = blockIdx.x * 256 + threadIdx.x;
    if (e < E) atomicAdd(&cnt[dst[e]], 1);
}

// each block scans 1024 counts -> exclusive offsets + block total
__global__ __launch_bounds__(256) void scan1_kernel(
    const int* __restrict__ cnt, int* __restrict__ offs,
    int* __restrict__ bsum, int N)
{
    __shared__ int s[256];
    int base = blockIdx.x * 1024 + threadIdx.x * 4;
    int v0 = (base + 0 < N) ? cnt[base + 0] : 0;
    int v1 = (base + 1 < N) ? cnt[base + 1] : 0;
    int v2 = (base + 2 < N) ? cnt[base + 2] : 0;
    int v3 = (base + 3 < N) ? cnt[base + 3] : 0;
    int tsum = v0 + v1 + v2 + v3;
    s[threadIdx.x] = tsum;
    __syncthreads();
    for (int off = 1; off < 256; off <<= 1) {
        int t = 0;
        if (threadIdx.x >= off) t = s[threadIdx.x - off];
        __syncthreads();
        if (threadIdx.x >= off) s[threadIdx.x] += t;
        __syncthreads();
    }
    int p = s[threadIdx.x] - tsum;   // exclusive prefix for this thread
    if (threadIdx.x == 255) bsum[blockIdx.x] = s[255];
    if (base + 0 < N) { offs[base + 0] = p; p += v0; }
    if (base + 1 < N) { offs[base + 1] = p; p += v1; }
    if (base + 2 < N) { offs[base + 2] = p; p += v2; }
    if (base + 3 < N) { offs[base + 3] = p; p += v3; }
}

// single block: exclusive-scan the (<=256) block sums in place
__global__ __launch_bounds__(256) void scan2_kernel(int* __restrict__ bsum, int nblk)
{
    __shared__ int s[256];
    int v = (threadIdx.x < nblk) ? bsum[threadIdx.x] : 0;
    s[threadIdx.x] = v;
    __syncthreads();
    for (int off = 1; off < 256; off <<= 1) {
        int t = 0;
        if (threadIdx.x >= off) t = s[threadIdx.x - off];
        __syncthreads();
        if (threadIdx.x >= off) s[threadIdx.x] += t;
        __syncthreads();
    }
    if (threadIdx.x < nblk) bsum[threadIdx.x] = s[threadIdx.x] - v;
}

__global__ __launch_bounds__(256) void scan3_kernel(
    int* __restrict__ offs, const int* __restrict__ bsum, int N, int E)
{
    int i = blockIdx.x * 256 + threadIdx.x;
    if (i < N) offs[i] += bsum[i >> 10];
    if (i == 0) offs[N] = E;
}

__global__ __launch_bounds__(256) void fill_kernel(
    const int* __restrict__ src, const int* __restrict__ dst,
    const int* __restrict__ offs, int* __restrict__ cursor,
    int* __restrict__ csr, int E)
{
    int e = blockIdx.x * 256 + threadIdx.x;
    if (e >= E) return;
    int d = dst[e];
    int p = atomicAdd(&cursor[d], 1);
    csr[offs[d] + p] = src[e];
}

// -------------------- gather aggregation: mean over in-neighbors -----------
// one wave per node; lane l accumulates features [2l, 2l+1]
__global__ __launch_bounds__(256) void agg_kernel(
    const float* __restrict__ h, const int* __restrict__ csr,
    const int* __restrict__ offs, float* __restrict__ mean, int N)
{
    int wid  = (blockIdx.x * 256 + threadIdx.x) >> 6;   // node id
    int lane = threadIdx.x & 63;
    if (wid >= N) return;
    int lo = offs[wid], hi = offs[wid + 1];
    float ax = 0.f, ay = 0.f;
    for (int base = lo; base < hi; base += 64) {
        int m = hi - base;
        int idx = 0;
        if (lane < m) idx = csr[base + lane];
        int cnt = m < 64 ? m : 64;
        int j = 0;
        for (; j + 3 < cnt; j += 4) {
            int s0 = __shfl(idx, j + 0);
            int s1 = __shfl(idx, j + 1);
            int s2 = __shfl(idx, j + 2);
            int s3 = __shfl(idx, j + 3);
            float2 v0 = *(const float2*)(h + (size_t)s0 * HID_F + lane * 2);
            float2 v1 = *(const float2*)(h + (size_t)s1 * HID_F + lane * 2);
            float2 v2 = *(const float2*)(h + (size_t)s2 * HID_F + lane * 2);
            float2 v3 = *(const float2*)(h + (size_t)s3 * HID_F + lane * 2);
            ax += v0.x + v1.x + v2.x + v3.x;
            ay += v0.y + v1.y + v2.y + v3.y;
        }
        for (; j < cnt; ++j) {
            int s0 = __shfl(idx, j);
            float2 v0 = *(const float2*)(h + (size_t)s0 * HID_F + lane * 2);
            ax += v0.x;
            ay += v0.y;
        }
    }
    float inv = (hi > lo) ? 1.0f / (float)(hi - lo) : 0.0f;
    float2 r;
    r.x = ax * inv;
    r.y = ay * inv;
    *(float2*)(mean + (size_t)wid * HID_F + lane * 2) = r;
}

// -------------------- SAGE update: z = h@Ws + mean@Wn + b + h; leaky -------
__global__ __launch_bounds__(256) void sage_kernel(
    const float* __restrict__ hin, const float* __restrict__ mean,
    const float* __restrict__ Ws, const float* __restrict__ Wn,
    const float* __restrict__ bias, float* __restrict__ hout, int N)
{
    __shared__ float s_h[32][HID_F];
    __shared__ float s_m[32][HID_F];
    int n0 = blockIdx.x * 32;
    for (int idx = threadIdx.x; idx < 32 * HID_F; idx += 256) {
        int nl = idx >> 7, i = idx & 127;
        int n = n0 + nl;
        float hv = 0.f, mv = 0.f;
        if (n < N) {
            hv = hin[(size_t)n * HID_F + i];
            mv = mean[(size_t)n * HID_F + i];
        }
        s_h[nl][i] = hv;
        s_m[nl][i] = mv;
    }
    __syncthreads();
    int og = threadIdx.x & 31;
    int ng = threadIdx.x >> 5;
    int o0 = og * 4, nl0 = ng * 4;
    float z[4][4] = {};
#pragma unroll 4
    for (int i = 0; i < HID_F; ++i) {
        float4 wsv = *(const float4*)(Ws + i * HID_F + o0);
        float4 wnv = *(const float4*)(Wn + i * HID_F + o0);
#pragma unroll
        for (int a = 0; a < 4; ++a) {
            float hv = s_h[nl0 + a][i];
            float mv = s_m[nl0 + a][i];
            z[a][0] = fmaf(hv, wsv.x, fmaf(mv, wnv.x, z[a][0]));
            z[a][1] = fmaf(hv, wsv.y, fmaf(mv, wnv.y, z[a][1]));
            z[a][2] = fmaf(hv, wsv.z, fmaf(mv, wnv.z, z[a][2]));
            z[a][3] = fmaf(hv, wsv.w, fmaf(mv, wnv.w, z[a][3]));
        }
    }
    float4 bv = *(const float4*)(bias + o0);
#pragma unroll
    for (int a = 0; a < 4; ++a) {
        int n = n0 + nl0 + a;
        if (n >= N) break;
        float4 r;
        r.x = z[a][0] + bv.x + s_h[nl0 + a][o0 + 0];
        r.y = z[a][1] + bv.y + s_h[nl0 + a][o0 + 1];
        r.z = z[a][2] + bv.z + s_h[nl0 + a][o0 + 2];
        r.w = z[a][3] + bv.w + s_h[nl0 + a][o0 + 3];
        r.x = r.x > 0.f ? r.x : 0.01f * r.x;
        r.y = r.y > 0.f ? r.y : 0.01f * r.y;
        r.z = r.z > 0.f ? r.z : 0.01f * r.z;
        r.w = r.w > 0.f ? r.w : 0.01f * r.w;
        *(float4*)(hout + (size_t)n * HID_F + o0) = r;
    }
}

// -------------------- mean pool per graph (gid sorted -> binary search) ----
__global__ __launch_bounds__(128) void pool_kernel(
    const float* __restrict__ h, const int* __restrict__ gid,
    float* __restrict__ ybuf, int N)
{
    int g = blockIdx.x;
    __shared__ int s_lo, s_hi;
    if (threadIdx.x == 0) {
        int lo = 0, hi = N;
        while (lo < hi) { int m = (lo + hi) >> 1; if (gid[m] < g) lo = m + 1; else hi = m; }
        s_lo = lo;
        int lo2 = lo, hi2 = N;
        while (lo2 < hi2) { int m = (lo2 + hi2) >> 1; if (gid[m] < g + 1) lo2 = m + 1; else hi2 = m; }
        s_hi = lo2;
    }
    __syncthreads();
    int lo = s_lo, hi = s_hi;
    float inv = 1.0f / fmaxf((float)(hi - lo), 1.0f);
    int o = threadIdx.x;
    float acc = 0.f;
    for (int n = lo; n < hi; ++n) acc += h[(size_t)n * HID_F + o];
    ybuf[g * HID_F + o] = acc * inv;
}

// -------------------- KAN readout layer 1: [512,128] -> [512,5] ------------
__global__ __launch_bounds__(256) void readout1_kernel(
    const float* __restrict__ ybuf, const float* __restrict__ coefr1,
    const float* __restrict__ sbr1, const float* __restrict__ ssr1,
    float* __restrict__ ymid)
{
    __shared__ float s_coef[HID_F * MID_F * NC];
    __shared__ float s_sb[HID_F * MID_F];
    for (int idx = threadIdx.x; idx < HID_F * MID_F * NC; idx += 256)
        s_coef[idx] = coefr1[idx] * ssr1[idx / NC];
    for (int idx = threadIdx.x; idx < HID_F * MID_F; idx += 256)
        s_sb[idx] = sbr1[idx];
    __syncthreads();
    int g = blockIdx.x * 256 + threadIdx.x;
    if (g >= NG) return;
    float acc[MID_F] = {0, 0, 0, 0, 0};
    for (int i = 0; i < HID_F; ++i) {
        float x = ybuf[g * HID_F + i];
        float B[NC];
        bspline11(x, B);
        float s = silu_f(x);
        const float* cp = s_coef + i * (MID_F * NC);
#pragma unroll
        for (int o = 0; o < MID_F; ++o) {
            float t = 0.f;
#pragma unroll
            for (int c = 0; c < NC; ++c) t = fmaf(cp[o * NC + c], B[c], t);
            acc[o] += s_sb[i * MID_F + o] * s + t;
        }
    }
#pragma unroll
    for (int o = 0; o < MID_F; ++o) ymid[g * MID_F + o] = acc[o];
}

// -------------------- KAN readout layer 2 + sigmoid: [512,5] -> [512,1] ----
__global__ __launch_bounds__(256) void readout2_kernel(
    const float* __restrict__ ymid, const float* __restrict__ coefr2,
    const float* __restrict__ sbr2, const float* __restrict__ ssr2,
    float* __restrict__ out)
{
    int g = blockIdx.x * 256 + threadIdx.x;
    if (g >= NG) return;
    float acc = 0.f;
#pragma unroll
    for (int i = 0; i < MID_F; ++i) {
        float x = ymid[g * MID_F + i];
        float B[NC];
        bspline11(x, B);
        float t = 0.f;
#pragma unroll
        for (int c = 0; c < NC; ++c) t = fmaf(coefr2[i * NC + c], B[c], t);
        acc += sbr2[i] * silu_f(x) + ssr2[i] * t;
    }
    out[g] = 1.0f / (1.0f + expf(-acc));
}

// ---------------------------------------------------------------------------
extern "C" void kernel_launch(void* const* d_in, const int* in_sizes, int n_in,
                              void* d_out, int out_size, void* d_ws, size_t ws_size,
                              hipStream_t stream)
{
    const float* h     = (const float*)d_in[0];
    const int*   src   = (const int*)d_in[1];
    const int*   dst   = (const int*)d_in[2];
    const int*   gid   = (const int*)d_in[3];
    const float* coef1 = (const float*)d_in[4];
    const float* sb1   = (const float*)d_in[5];
    const float* ss1   = (const float*)d_in[6];
    const float* coef2 = (const float*)d_in[7];
    const float* sb2   = (const float*)d_in[8];
    const float* ss2   = (const float*)d_in[9];
    const float* Ws0   = (const float*)d_in[10];
    const float* Wn0   = (const float*)d_in[11];
    const float* b0    = (const float*)d_in[12];
    const float* Ws1   = (const float*)d_in[13];
    const float* Wn1   = (const float*)d_in[14];
    const float* b1    = (const float*)d_in[15];
    const float* coefr1= (const float*)d_in[16];
    const float* sbr1  = (const float*)d_in[17];
    const float* ssr1  = (const float*)d_in[18];
    const float* coefr2= (const float*)d_in[19];
    const float* sbr2  = (const float*)d_in[20];
    const float* ssr2  = (const float*)d_in[21];

    const int N = in_sizes[0] / IN_F;   // 100000
    const int E = in_sizes[1];          // 1600000

    // ---- workspace layout ----
    float* ws   = (float*)d_ws;
    float* mid  = ws;                          // N*5
    float* h0   = mid + (size_t)N * MID_F;     // N*128
    float* h1   = h0 + (size_t)N * HID_F;      // N*128
    float* mean = h1 + (size_t)N * HID_F;      // N*128
    float* ybuf = mean + (size_t)N * HID_F;    // 512*128
    float* ymid = ybuf + NG * HID_F;           // 512*5
    int*   cnt  = (int*)(ymid + NG * MID_F);   // N   (reused as cursor)
    int*   offs = cnt + N;                     // N+1
    int*   bsum = offs + N + 1;                // 256
    int*   csr  = bsum + 256;                  // E

    const int nblk = (N + 1023) / 1024;

    // KAN encoder
    enc1_kernel<<<(N + 255) / 256, 256, 0, stream>>>(h, coef1, sb1, ss1, mid, N);
    enc2_kernel<<<2048, 256, 0, stream>>>(mid, coef2, sb2, ss2, h0, N);

    // CSR build (once; reused by both SAGE layers)
    hipMemsetAsync(cnt, 0, (size_t)N * sizeof(int), stream);
    count_kernel<<<(E + 255) / 256, 256, 0, stream>>>(dst, cnt, E);
    scan1_kernel<<<nblk, 256, 0, stream>>>(cnt, offs, bsum, N);
    scan2_kernel<<<1, 256, 0, stream>>>(bsum, nblk);
    scan3_kernel<<<(N + 255) / 256, 256, 0, stream>>>(offs, bsum, N, E);
    hipMemsetAsync(cnt, 0, (size_t)N * sizeof(int), stream);   // cnt -> cursor
    fill_kernel<<<(E + 255) / 256, 256, 0, stream>>>(src, dst, offs, cnt, csr, E);

    // SAGE layer 0
    agg_kernel<<<(N * 64 + 255) / 256, 256, 0, stream>>>(h0, csr, offs, mean, N);
    sage_kernel<<<(N + 31) / 32, 256, 0, stream>>>(h0, mean, Ws0, Wn0, b0, h1, N);

    // SAGE layer 1
    agg_kernel<<<(N * 64 + 255) / 256, 256, 0, stream>>>(h1, csr, offs, mean, N);
    sage_kernel<<<(N + 31) / 32, 256, 0, stream>>>(h1, mean, Ws1, Wn1, b1, h0, N);

    // pool + readout
    pool_kernel<<<NG, 128, 0, stream>>>(h0, gid, ybuf, N);
    readout1_kernel<<<2, 256, 0, stream>>>(ybuf, coefr1, sbr1, ssr1, ymid);
    readout2_kernel<<<2, 256, 0, stream>>>(ymid, coefr2, sbr2, ssr2, (float*)d_out);
}

// Round 4
// 1020.961 us; speedup vs baseline: 6.1989x; 1.1532x over previous
//
#include <hip/hip_runtime.h>

// ---------------------------------------------------------------------------
// KAN-GNN forward on MI355X.  Sizes (fixed by reference): N=100000 nodes,
// E=1600000 edges, IN=64, MID=5, HID=128, OUT=1, NG=512 graphs, C=11 basis.
// Round 3 (resubmit; round-3 bench hit GPUAcquisitionTimeout): fix readout1
// occupancy (2 blocks -> 512 blocks, was 168us @ 0.09% occupancy) and fuse
// graph-mean pooling into it.
// ---------------------------------------------------------------------------

#define IN_F   64
#define MID_F  5
#define HID_F  128
#define NG     512
#define NC     11   // G_GRID + K_SPLINE = 8 + 3

// Cubic B-spline basis on uniform knots t_j = -1.75 + 0.25 j, j=0..14.
__device__ __forceinline__ void bspline11(float x, float* __restrict__ B) {
    float b[14];
#pragma unroll
    for (int j = 0; j < 14; ++j) {
        float tj = -1.75f + 0.25f * j;
        b[j] = (x >= tj && x < tj + 0.25f) ? 1.0f : 0.0f;
    }
#pragma unroll
    for (int d = 1; d <= 3; ++d) {
        float inv = 1.0f / (0.25f * d);
#pragma unroll 14
        for (int j = 0; j < 14 - 3; ++j) {
            if (j < 14 - d) {
                float tj   = -1.75f + 0.25f * j;
                float tjd1 = tj + 0.25f * (d + 1);
                b[j] = ((x - tj) * b[j] + (tjd1 - x) * b[j + 1]) * inv;
            }
        }
        if (d < 3) {
#pragma unroll
            for (int j = 11; j < 14; ++j) {
                if (j < 14 - d) {
                    float tj   = -1.75f + 0.25f * j;
                    float tjd1 = tj + 0.25f * (d + 1);
                    b[j] = ((x - tj) * b[j] + (tjd1 - x) * b[j + 1]) * inv;
                }
            }
        }
    }
#pragma unroll
    for (int j = 0; j < NC; ++j) B[j] = b[j];
}

__device__ __forceinline__ float silu_f(float x) { return x / (1.0f + expf(-x)); }

// -------------------- KAN encoder layer 1: [N,64] -> [N,5] -----------------
__global__ __launch_bounds__(256) void enc1_kernel(
    const float* __restrict__ h, const float* __restrict__ coef1,
    const float* __restrict__ sb1, const float* __restrict__ ss1,
    float* __restrict__ mid, int N)
{
    __shared__ float s_coef[IN_F * MID_F * NC];
    __shared__ float s_sb[IN_F * MID_F];
    for (int idx = threadIdx.x; idx < IN_F * MID_F * NC; idx += 256)
        s_coef[idx] = coef1[idx] * ss1[idx / NC];
    for (int idx = threadIdx.x; idx < IN_F * MID_F; idx += 256)
        s_sb[idx] = sb1[idx];
    __syncthreads();

    int n = blockIdx.x * 256 + threadIdx.x;
    if (n >= N) return;
    float acc[MID_F] = {0, 0, 0, 0, 0};
    const float* hr = h + (size_t)n * IN_F;
    for (int i = 0; i < IN_F; ++i) {
        float x = hr[i];
        float B[NC];
        bspline11(x, B);
        float s = silu_f(x);
        const float* cp = s_coef + i * (MID_F * NC);
        const float* sp = s_sb + i * MID_F;
#pragma unroll
        for (int o = 0; o < MID_F; ++o) {
            float t = 0.f;
#pragma unroll
            for (int c = 0; c < NC; ++c) t = fmaf(cp[o * NC + c], B[c], t);
            acc[o] += sp[o] * s + t;
        }
    }
#pragma unroll
    for (int o = 0; o < MID_F; ++o) mid[(size_t)n * MID_F + o] = acc[o];
}

// -------------------- KAN encoder layer 2: [N,5] -> [N,128] ----------------
__global__ __launch_bounds__(256) void enc2_kernel(
    const float* __restrict__ mid, const float* __restrict__ coef2,
    const float* __restrict__ sb2, const float* __restrict__ ss2,
    float* __restrict__ h0, int N)
{
    __shared__ float s_coef[MID_F * HID_F * NC];  // 7040 floats
    __shared__ float s_sb[MID_F * HID_F];
    __shared__ float s_B[2][MID_F][NC];
    __shared__ float s_sil[2][MID_F];
    for (int idx = threadIdx.x; idx < MID_F * HID_F * NC; idx += 256)
        s_coef[idx] = coef2[idx] * ss2[idx / NC];
    for (int idx = threadIdx.x; idx < MID_F * HID_F; idx += 256)
        s_sb[idx] = sb2[idx];

    int nTiles = (N + 1) / 2;
    for (int tile = blockIdx.x; tile < nTiles; tile += gridDim.x) {
        __syncthreads();
        int ln = threadIdx.x >> 7;
        int o  = threadIdx.x & 127;
        int n  = tile * 2 + ln;
        if (o < MID_F && n < N) {
            float x = mid[(size_t)n * MID_F + o];
            bspline11(x, &s_B[ln][o][0]);
            s_sil[ln][o] = silu_f(x);
        }
        __syncthreads();
        if (n < N) {
            float z = 0.f;
#pragma unroll
            for (int i = 0; i < MID_F; ++i) {
                const float* cp = s_coef + (i * HID_F + o) * NC;
                float t = 0.f;
#pragma unroll
                for (int c = 0; c < NC; ++c) t = fmaf(cp[c], s_B[ln][i][c], t);
                z += s_sb[i * HID_F + o] * s_sil[ln][i] + t;
            }
            h0[(size_t)n * HID_F + o] = z;
        }
    }
}

// -------------------- CSR build: count / scan / fill -----------------------
__global__ __launch_bounds__(256) void count_kernel(
    const int* __restrict__ dst, int* __restrict__ cnt, int E)
{
    int e = blockIdx.x * 256 + threadIdx.x;
    if (e < E) atomicAdd(&cnt[dst[e]], 1);
}

__global__ __launch_bounds__(256) void scan1_kernel(
    const int* __restrict__ cnt, int* __restrict__ offs,
    int* __restrict__ bsum, int N)
{
    __shared__ int s[256];
    int base = blockIdx.x * 1024 + threadIdx.x * 4;
    int v0 = (base + 0 < N) ? cnt[base + 0] : 0;
    int v1 = (base + 1 < N) ? cnt[base + 1] : 0;
    int v2 = (base + 2 < N) ? cnt[base + 2] : 0;
    int v3 = (base + 3 < N) ? cnt[base + 3] : 0;
    int tsum = v0 + v1 + v2 + v3;
    s[threadIdx.x] = tsum;
    __syncthreads();
    for (int off = 1; off < 256; off <<= 1) {
        int t = 0;
        if (threadIdx.x >= off) t = s[threadIdx.x - off];
        __syncthreads();
        if (threadIdx.x >= off) s[threadIdx.x] += t;
        __syncthreads();
    }
    int p = s[threadIdx.x] - tsum;
    if (threadIdx.x == 255) bsum[blockIdx.x] = s[255];
    if (base + 0 < N) { offs[base + 0] = p; p += v0; }
    if (base + 1 < N) { offs[base + 1] = p; p += v1; }
    if (base + 2 < N) { offs[base + 2] = p; p += v2; }
    if (base + 3 < N) { offs[base + 3] = p; p += v3; }
}

__global__ __launch_bounds__(256) void scan2_kernel(int* __restrict__ bsum, int nblk)
{
    __shared__ int s[256];
    int v = (threadIdx.x < nblk) ? bsum[threadIdx.x] : 0;
    s[threadIdx.x] = v;
    __syncthreads();
    for (int off = 1; off < 256; off <<= 1) {
        int t = 0;
        if (threadIdx.x >= off) t = s[threadIdx.x - off];
        __syncthreads();
        if (threadIdx.x >= off) s[threadIdx.x] += t;
        __syncthreads();
    }
    if (threadIdx.x < nblk) bsum[threadIdx.x] = s[threadIdx.x] - v;
}

__global__ __launch_bounds__(256) void scan3_kernel(
    int* __restrict__ offs, const int* __restrict__ bsum, int N, int E)
{
    int i = blockIdx.x * 256 + threadIdx.x;
    if (i < N) offs[i] += bsum[i >> 10];
    if (i == 0) offs[N] = E;
}

__global__ __launch_bounds__(256) void fill_kernel(
    const int* __restrict__ src, const int* __restrict__ dst,
    const int* __restrict__ offs, int* __restrict__ cursor,
    int* __restrict__ csr, int E)
{
    int e = blockIdx.x * 256 + threadIdx.x;
    if (e >= E) return;
    int d = dst[e];
    int p = atomicAdd(&cursor[d], 1);
    csr[offs[d] + p] = src[e];
}

// -------------------- gather aggregation: mean over in-neighbors -----------
__global__ __launch_bounds__(256) void agg_kernel(
    const float* __restrict__ h, const int* __restrict__ csr,
    const int* __restrict__ offs, float* __restrict__ mean, int N)
{
    int wid  = (blockIdx.x * 256 + threadIdx.x) >> 6;   // node id
    int lane = threadIdx.x & 63;
    if (wid >= N) return;
    int lo = offs[wid], hi = offs[wid + 1];
    float ax = 0.f, ay = 0.f;
    for (int base = lo; base < hi; base += 64) {
        int m = hi - base;
        int idx = 0;
        if (lane < m) idx = csr[base + lane];
        int cnt = m < 64 ? m : 64;
        int j = 0;
        for (; j + 3 < cnt; j += 4) {
            int s0 = __shfl(idx, j + 0);
            int s1 = __shfl(idx, j + 1);
            int s2 = __shfl(idx, j + 2);
            int s3 = __shfl(idx, j + 3);
            float2 v0 = *(const float2*)(h + (size_t)s0 * HID_F + lane * 2);
            float2 v1 = *(const float2*)(h + (size_t)s1 * HID_F + lane * 2);
            float2 v2 = *(const float2*)(h + (size_t)s2 * HID_F + lane * 2);
            float2 v3 = *(const float2*)(h + (size_t)s3 * HID_F + lane * 2);
            ax += v0.x + v1.x + v2.x + v3.x;
            ay += v0.y + v1.y + v2.y + v3.y;
        }
        for (; j < cnt; ++j) {
            int s0 = __shfl(idx, j);
            float2 v0 = *(const float2*)(h + (size_t)s0 * HID_F + lane * 2);
            ax += v0.x;
            ay += v0.y;
        }
    }
    float inv = (hi > lo) ? 1.0f / (float)(hi - lo) : 0.0f;
    float2 r;
    r.x = ax * inv;
    r.y = ay * inv;
    *(float2*)(mean + (size_t)wid * HID_F + lane * 2) = r;
}

// -------------------- SAGE update: z = h@Ws + mean@Wn + b + h; leaky -------
__global__ __launch_bounds__(256) void sage_kernel(
    const float* __restrict__ hin, const float* __restrict__ mean,
    const float* __restrict__ Ws, const float* __restrict__ Wn,
    const float* __restrict__ bias, float* __restrict__ hout, int N)
{
    __shared__ float s_h[32][HID_F];
    __shared__ float s_m[32][HID_F];
    int n0 = blockIdx.x * 32;
    for (int idx = threadIdx.x; idx < 32 * HID_F; idx += 256) {
        int nl = idx >> 7, i = idx & 127;
        int n = n0 + nl;
        float hv = 0.f, mv = 0.f;
        if (n < N) {
            hv = hin[(size_t)n * HID_F + i];
            mv = mean[(size_t)n * HID_F + i];
        }
        s_h[nl][i] = hv;
        s_m[nl][i] = mv;
    }
    __syncthreads();
    int og = threadIdx.x & 31;
    int ng = threadIdx.x >> 5;
    int o0 = og * 4, nl0 = ng * 4;
    float z[4][4] = {};
#pragma unroll 4
    for (int i = 0; i < HID_F; ++i) {
        float4 wsv = *(const float4*)(Ws + i * HID_F + o0);
        float4 wnv = *(const float4*)(Wn + i * HID_F + o0);
#pragma unroll
        for (int a = 0; a < 4; ++a) {
            float hv = s_h[nl0 + a][i];
            float mv = s_m[nl0 + a][i];
            z[a][0] = fmaf(hv, wsv.x, fmaf(mv, wnv.x, z[a][0]));
            z[a][1] = fmaf(hv, wsv.y, fmaf(mv, wnv.y, z[a][1]));
            z[a][2] = fmaf(hv, wsv.z, fmaf(mv, wnv.z, z[a][2]));
            z[a][3] = fmaf(hv, wsv.w, fmaf(mv, wnv.w, z[a][3]));
        }
    }
    float4 bv = *(const float4*)(bias + o0);
#pragma unroll
    for (int a = 0; a < 4; ++a) {
        int n = n0 + nl0 + a;
        if (n >= N) break;
        float4 r;
        r.x = z[a][0] + bv.x + s_h[nl0 + a][o0 + 0];
        r.y = z[a][1] + bv.y + s_h[nl0 + a][o0 + 1];
        r.z = z[a][2] + bv.z + s_h[nl0 + a][o0 + 2];
        r.w = z[a][3] + bv.w + s_h[nl0 + a][o0 + 3];
        r.x = r.x > 0.f ? r.x : 0.01f * r.x;
        r.y = r.y > 0.f ? r.y : 0.01f * r.y;
        r.z = r.z > 0.f ? r.z : 0.01f * r.z;
        r.w = r.w > 0.f ? r.w : 0.01f * r.w;
        *(float4*)(hout + (size_t)n * HID_F + o0) = r;
    }
}

// ------------- fused graph-mean pool + KAN readout layer 1 ------------------
// one block per graph, 128 threads (thread i owns feature i)
__global__ __launch_bounds__(128) void pool_readout1_kernel(
    const float* __restrict__ h, const int* __restrict__ gid,
    const float* __restrict__ coefr1, const float* __restrict__ sbr1,
    const float* __restrict__ ssr1, float* __restrict__ ymid, int N)
{
    int g = blockIdx.x;
    int i = threadIdx.x;

    // node range for graph g (gid sorted)
    int lo = 0, hi = N;
    while (lo < hi) { int m = (lo + hi) >> 1; if (gid[m] < g) lo = m + 1; else hi = m; }
    int lo2 = lo, hi2 = N;
    while (lo2 < hi2) { int m = (lo2 + hi2) >> 1; if (gid[m] < g + 1) lo2 = m + 1; else hi2 = m; }

    // mean over nodes for feature i
    float acc = 0.f;
    for (int n = lo; n < lo2; ++n) acc += h[(size_t)n * HID_F + i];
    float x = acc * (1.0f / fmaxf((float)(lo2 - lo), 1.0f));

    // KAN contribution of input feature i to the 5 outputs
    float B[NC];
    bspline11(x, B);
    float s = silu_f(x);
    const float* cp  = coefr1 + (size_t)i * (MID_F * NC);
    const float* ssp = ssr1 + (size_t)i * MID_F;
    const float* sbp = sbr1 + (size_t)i * MID_F;
    float p[MID_F];
#pragma unroll
    for (int o = 0; o < MID_F; ++o) {
        float t = 0.f;
#pragma unroll
        for (int c = 0; c < NC; ++c) t = fmaf(cp[o * NC + c], B[c], t);
        p[o] = sbp[o] * s + ssp[o] * t;
    }

    // reduce over 128 threads: wave shuffle then cross-wave via LDS
#pragma unroll
    for (int off = 32; off >= 1; off >>= 1) {
#pragma unroll
        for (int o = 0; o < MID_F; ++o) p[o] += __shfl_down(p[o], off);
    }
    __shared__ float s_part[2][MID_F];
    int lane = threadIdx.x & 63, w = threadIdx.x >> 6;
    if (lane == 0) {
#pragma unroll
        for (int o = 0; o < MID_F; ++o) s_part[w][o] = p[o];
    }
    __syncthreads();
    if (threadIdx.x < MID_F)
        ymid[g * MID_F + threadIdx.x] = s_part[0][threadIdx.x] + s_part[1][threadIdx.x];
}

// -------------------- KAN readout layer 2 + sigmoid: [512,5] -> [512,1] ----
__global__ __launch_bounds__(256) void readout2_kernel(
    const float* __restrict__ ymid, const float* __restrict__ coefr2,
    const float* __restrict__ sbr2, const float* __restrict__ ssr2,
    float* __restrict__ out)
{
    int g = blockIdx.x * 256 + threadIdx.x;
    if (g >= NG) return;
    float acc = 0.f;
#pragma unroll
    for (int i = 0; i < MID_F; ++i) {
        float x = ymid[g * MID_F + i];
        float B[NC];
        bspline11(x, B);
        float t = 0.f;
#pragma unroll
        for (int c = 0; c < NC; ++c) t = fmaf(coefr2[i * NC + c], B[c], t);
        acc += sbr2[i] * silu_f(x) + ssr2[i] * t;
    }
    out[g] = 1.0f / (1.0f + expf(-acc));
}

// ---------------------------------------------------------------------------
extern "C" void kernel_launch(void* const* d_in, const int* in_sizes, int n_in,
                              void* d_out, int out_size, void* d_ws, size_t ws_size,
                              hipStream_t stream)
{
    const float* h     = (const float*)d_in[0];
    const int*   src   = (const int*)d_in[1];
    const int*   dst   = (const int*)d_in[2];
    const int*   gid   = (const int*)d_in[3];
    const float* coef1 = (const float*)d_in[4];
    const float* sb1   = (const float*)d_in[5];
    const float* ss1   = (const float*)d_in[6];
    const float* coef2 = (const float*)d_in[7];
    const float* sb2   = (const float*)d_in[8];
    const float* ss2   = (const float*)d_in[9];
    const float* Ws0   = (const float*)d_in[10];
    const float* Wn0   = (const float*)d_in[11];
    const float* b0    = (const float*)d_in[12];
    const float* Ws1   = (const float*)d_in[13];
    const float* Wn1   = (const float*)d_in[14];
    const float* b1    = (const float*)d_in[15];
    const float* coefr1= (const float*)d_in[16];
    const float* sbr1  = (const float*)d_in[17];
    const float* ssr1  = (const float*)d_in[18];
    const float* coefr2= (const float*)d_in[19];
    const float* sbr2  = (const float*)d_in[20];
    const float* ssr2  = (const float*)d_in[21];

    const int N = in_sizes[0] / IN_F;   // 100000
    const int E = in_sizes[1];          // 1600000

    // ---- workspace layout ----
    float* ws   = (float*)d_ws;
    float* mid  = ws;                          // N*5
    float* h0   = mid + (size_t)N * MID_F;     // N*128
    float* h1   = h0 + (size_t)N * HID_F;      // N*128
    float* mean = h1 + (size_t)N * HID_F;      // N*128
    float* ymid = mean + (size_t)N * HID_F;    // 512*5
    int*   cnt  = (int*)(ymid + NG * MID_F);   // N   (reused as cursor)
    int*   offs = cnt + N;                     // N+1
    int*   bsum = offs + N + 1;                // 256
    int*   csr  = bsum + 256;                  // E

    const int nblk = (N + 1023) / 1024;

    // KAN encoder
    enc1_kernel<<<(N + 255) / 256, 256, 0, stream>>>(h, coef1, sb1, ss1, mid, N);
    enc2_kernel<<<2048, 256, 0, stream>>>(mid, coef2, sb2, ss2, h0, N);

    // CSR build (once; reused by both SAGE layers)
    hipMemsetAsync(cnt, 0, (size_t)N * sizeof(int), stream);
    count_kernel<<<(E + 255) / 256, 256, 0, stream>>>(dst, cnt, E);
    scan1_kernel<<<nblk, 256, 0, stream>>>(cnt, offs, bsum, N);
    scan2_kernel<<<1, 256, 0, stream>>>(bsum, nblk);
    scan3_kernel<<<(N + 255) / 256, 256, 0, stream>>>(offs, bsum, N, E);
    hipMemsetAsync(cnt, 0, (size_t)N * sizeof(int), stream);   // cnt -> cursor
    fill_kernel<<<(E + 255) / 256, 256, 0, stream>>>(src, dst, offs, cnt, csr, E);

    // SAGE layer 0
    agg_kernel<<<(N * 64 + 255) / 256, 256, 0, stream>>>(h0, csr, offs, mean, N);
    sage_kernel<<<(N + 31) / 32, 256, 0, stream>>>(h0, mean, Ws0, Wn0, b0, h1, N);

    // SAGE layer 1
    agg_kernel<<<(N * 64 + 255) / 256, 256, 0, stream>>>(h1, csr, offs, mean, N);
    sage_kernel<<<(N + 31) / 32, 256, 0, stream>>>(h1, mean, Ws1, Wn1, b1, h0, N);

    // fused pool + readout
    pool_readout1_kernel<<<NG, 128, 0, stream>>>(h0, gid, coefr1, sbr1, ssr1, ymid, N);
    readout2_kernel<<<2, 256, 0, stream>>>(ymid, coefr2, sbr2, ssr2, (float*)d_out);
}

// Round 5
// 896.447 us; speedup vs baseline: 7.0599x; 1.1389x over previous
//
#include <hip/hip_runtime.h>

// ---------------------------------------------------------------------------
// KAN-GNN forward on MI355X.  Sizes (fixed by reference): N=100000 nodes,
// E=1600000 edges, IN=64, MID=5, HID=128, OUT=1, NG=512 graphs, C=11 basis.
// Round 5: replace per-element Cox-de Boor + LDS coef dot (55 ds_read + 55
// FMA per thread in enc2) with precomputed piecewise-cubic polynomial tables
// (u-monomial basis, ss folded in): 1 float4 L2 load + 4 FMA per (node,i).
// Poly tables aliased onto `mean` (dead until agg0) -> zero extra workspace.
// ---------------------------------------------------------------------------

#define IN_F   64
#define MID_F  5
#define HID_F  128
#define NG     512
#define NC     11   // G_GRID + K_SPLINE = 8 + 3
#define NJ     14   // intervals of [-1.75, 1.75) at h=0.25

// Cubic B-spline basis on uniform knots t_j = -1.75 + 0.25 j, j=0..14.
// (still used by the tiny readout kernels)
__device__ __forceinline__ void bspline11(float x, float* __restrict__ B) {
    float b[14];
#pragma unroll
    for (int j = 0; j < 14; ++j) {
        float tj = -1.75f + 0.25f * j;
        b[j] = (x >= tj && x < tj + 0.25f) ? 1.0f : 0.0f;
    }
#pragma unroll
    for (int d = 1; d <= 3; ++d) {
        float inv = 1.0f / (0.25f * d);
#pragma unroll 14
        for (int j = 0; j < 14 - 3; ++j) {
            if (j < 14 - d) {
                float tj   = -1.75f + 0.25f * j;
                float tjd1 = tj + 0.25f * (d + 1);
                b[j] = ((x - tj) * b[j] + (tjd1 - x) * b[j + 1]) * inv;
            }
        }
        if (d < 3) {
#pragma unroll
            for (int j = 11; j < 14; ++j) {
                if (j < 14 - d) {
                    float tj   = -1.75f + 0.25f * j;
                    float tjd1 = tj + 0.25f * (d + 1);
                    b[j] = ((x - tj) * b[j] + (tjd1 - x) * b[j + 1]) * inv;
                }
            }
        }
    }
#pragma unroll
    for (int j = 0; j < NC; ++j) B[j] = b[j];
}

__device__ __forceinline__ float silu_f(float x) { return x / (1.0f + expf(-x)); }

// ---- build piecewise-cubic tables: poly[idx][4] = {a,b,c,d} in local u ----
// On interval j, active bases are c = j-3..j (clipped to [0,10]); weights:
// w0=(1-u)^3/6, w1=(3u^3-6u^2+4)/6, w2=(-3u^3+3u^2+3u+1)/6, w3=u^3/6.
__device__ __forceinline__ float4 poly_from_coefs(float c0, float c1, float c2, float c3) {
    const float s = 1.0f / 6.0f;
    float4 p;
    p.x = (-c0 + 3.f*c1 - 3.f*c2 + c3) * s;   // u^3
    p.y = ( 3.f*c0 - 6.f*c1 + 3.f*c2) * s;    // u^2
    p.z = (-3.f*c0 + 3.f*c2) * s;             // u^1
    p.w = (      c0 + 4.f*c1 + c2) * s;       // 1
    return p;
}

// poly1 layout: [i (64)][j (14)][o (5)][4]
__global__ __launch_bounds__(256) void build_poly1_kernel(
    const float* __restrict__ coef1, const float* __restrict__ ss1,
    float* __restrict__ poly1)
{
    int idx = blockIdx.x * 256 + threadIdx.x;
    if (idx >= IN_F * NJ * MID_F) return;
    int o = idx % MID_F;
    int t = idx / MID_F;
    int j = t % NJ;
    int i = t / NJ;
    float ss = ss1[i * MID_F + o];
    float c[4];
#pragma unroll
    for (int k = 0; k < 4; ++k) {
        int cc = j - 3 + k;
        c[k] = (cc >= 0 && cc <= 10) ? coef1[(i * MID_F + o) * NC + cc] * ss : 0.f;
    }
    *(float4*)(poly1 + (size_t)idx * 4) = poly_from_coefs(c[0], c[1], c[2], c[3]);
}

// poly2 layout: [i (5)][j (14)][o (128)][4]
__global__ __launch_bounds__(256) void build_poly2_kernel(
    const float* __restrict__ coef2, const float* __restrict__ ss2,
    float* __restrict__ poly2)
{
    int idx = blockIdx.x * 256 + threadIdx.x;
    if (idx >= MID_F * NJ * HID_F) return;
    int o = idx & 127;
    int t = idx >> 7;
    int j = t % NJ;
    int i = t / NJ;
    float ss = ss2[i * HID_F + o];
    float c[4];
#pragma unroll
    for (int k = 0; k < 4; ++k) {
        int cc = j - 3 + k;
        c[k] = (cc >= 0 && cc <= 10) ? coef2[(i * HID_F + o) * NC + cc] * ss : 0.f;
    }
    *(float4*)(poly2 + (size_t)idx * 4) = poly_from_coefs(c[0], c[1], c[2], c[3]);
}

// -------------------- KAN encoder layer 1: [N,64] -> [N,5] -----------------
// thread = node; per input i: interval+u, 5 float4 poly loads (L1-hot row),
// 20 FMA Horner + 5 FMA silu term.
__global__ __launch_bounds__(256) void enc1_kernel(
    const float* __restrict__ h, const float* __restrict__ poly1,
    const float* __restrict__ sb1, float* __restrict__ mid, int N)
{
    __shared__ float s_sb[IN_F * MID_F];
    for (int idx = threadIdx.x; idx < IN_F * MID_F; idx += 256)
        s_sb[idx] = sb1[idx];
    __syncthreads();

    int n = blockIdx.x * 256 + threadIdx.x;
    if (n >= N) return;
    const float* hr = h + (size_t)n * IN_F;
    float acc[MID_F] = {0, 0, 0, 0, 0};

#pragma unroll 4
    for (int i4 = 0; i4 < IN_F; i4 += 4) {
        float4 xv = *(const float4*)(hr + i4);
        float xs[4] = {xv.x, xv.y, xv.z, xv.w};
#pragma unroll
        for (int k = 0; k < 4; ++k) {
            int i = i4 + k;
            float x = xs[k];
            float xf = (x + 1.75f) * 4.0f;
            float fj = floorf(xf);
            int j0 = (int)fj;
            j0 = j0 < 0 ? 0 : (j0 > 13 ? 13 : j0);
            float u = xf - fj;
            float msk = (x >= -1.75f && x < 1.75f) ? 1.0f : 0.0f;
            float s = silu_f(x);
            const float* pp = poly1 + ((size_t)(i * NJ + j0) * MID_F) * 4;
#pragma unroll
            for (int o = 0; o < MID_F; ++o) {
                float4 p = *(const float4*)(pp + 4 * o);
                float t = fmaf(fmaf(fmaf(p.x, u, p.y), u, p.z), u, p.w);
                acc[o] = fmaf(s_sb[i * MID_F + o], s, acc[o]);
                acc[o] = fmaf(t, msk, acc[o]);
            }
        }
    }
#pragma unroll
    for (int o = 0; o < MID_F; ++o) mid[(size_t)n * MID_F + o] = acc[o];
}

// -------------------- KAN encoder layer 2: [N,5] -> [N,128] ----------------
// 2 nodes x 128 outputs per block; per (node,i): broadcast j0/u/silu from
// LDS, coalesced float4 poly2 load, Horner + 2 FMA.
__global__ __launch_bounds__(256) void enc2_kernel(
    const float* __restrict__ mid, const float* __restrict__ poly2,
    const float* __restrict__ sb2, float* __restrict__ h0, int N)
{
    __shared__ float s_u[2][MID_F], s_sil[2][MID_F], s_msk[2][MID_F];
    __shared__ int   s_j0[2][MID_F];
    int o  = threadIdx.x & 127;
    int ln = threadIdx.x >> 7;

    float sbr[MID_F];
#pragma unroll
    for (int i = 0; i < MID_F; ++i) sbr[i] = sb2[i * HID_F + o];

    int nTiles = (N + 1) / 2;
    for (int tile = blockIdx.x; tile < nTiles; tile += gridDim.x) {
        __syncthreads();
        if (threadIdx.x < 2 * MID_F) {
            int l = threadIdx.x / MID_F, i = threadIdx.x % MID_F;
            int n = tile * 2 + l;
            float x = (n < N) ? mid[(size_t)n * MID_F + i] : 0.f;
            float xf = (x + 1.75f) * 4.0f;
            float fj = floorf(xf);
            int j0 = (int)fj;
            j0 = j0 < 0 ? 0 : (j0 > 13 ? 13 : j0);
            s_j0[l][i]  = j0;
            s_u[l][i]   = xf - fj;
            s_msk[l][i] = (x >= -1.75f && x < 1.75f) ? 1.0f : 0.0f;
            s_sil[l][i] = silu_f(x);
        }
        __syncthreads();
        int n = tile * 2 + ln;
        if (n < N) {
            float z = 0.f;
#pragma unroll
            for (int i = 0; i < MID_F; ++i) {
                float4 p = *(const float4*)(poly2 +
                            ((size_t)((i * NJ + s_j0[ln][i]) * HID_F + o)) * 4);
                float u = s_u[ln][i];
                float t = fmaf(fmaf(fmaf(p.x, u, p.y), u, p.z), u, p.w);
                z = fmaf(sbr[i], s_sil[ln][i], z);
                z = fmaf(t, s_msk[ln][i], z);
            }
            h0[(size_t)n * HID_F + o] = z;
        }
    }
}

// -------------------- CSR build: count / scan / fill -----------------------
__global__ __launch_bounds__(256) void count_kernel(
    const int* __restrict__ dst, int* __restrict__ cnt, int E)
{
    int e = blockIdx.x * 256 + threadIdx.x;
    if (e < E) atomicAdd(&cnt[dst[e]], 1);
}

__global__ __launch_bounds__(256) void scan1_kernel(
    const int* __restrict__ cnt, int* __restrict__ offs,
    int* __restrict__ bsum, int N)
{
    __shared__ int s[256];
    int base = blockIdx.x * 1024 + threadIdx.x * 4;
    int v0 = (base + 0 < N) ? cnt[base + 0] : 0;
    int v1 = (base + 1 < N) ? cnt[base + 1] : 0;
    int v2 = (base + 2 < N) ? cnt[base + 2] : 0;
    int v3 = (base + 3 < N) ? cnt[base + 3] : 0;
    int tsum = v0 + v1 + v2 + v3;
    s[threadIdx.x] = tsum;
    __syncthreads();
    for (int off = 1; off < 256; off <<= 1) {
        int t = 0;
        if (threadIdx.x >= off) t = s[threadIdx.x - off];
        __syncthreads();
        if (threadIdx.x >= off) s[threadIdx.x] += t;
        __syncthreads();
    }
    int p = s[threadIdx.x] - tsum;
    if (threadIdx.x == 255) bsum[blockIdx.x] = s[255];
    if (base + 0 < N) { offs[base + 0] = p; p += v0; }
    if (base + 1 < N) { offs[base + 1] = p; p += v1; }
    if (base + 2 < N) { offs[base + 2] = p; p += v2; }
    if (base + 3 < N) { offs[base + 3] = p; p += v3; }
}

__global__ __launch_bounds__(256) void scan2_kernel(int* __restrict__ bsum, int nblk)
{
    __shared__ int s[256];
    int v = (threadIdx.x < nblk) ? bsum[threadIdx.x] : 0;
    s[threadIdx.x] = v;
    __syncthreads();
    for (int off = 1; off < 256; off <<= 1) {
        int t = 0;
        if (threadIdx.x >= off) t = s[threadIdx.x - off];
        __syncthreads();
        if (threadIdx.x >= off) s[threadIdx.x] += t;
        __syncthreads();
    }
    if (threadIdx.x < nblk) bsum[threadIdx.x] = s[threadIdx.x] - v;
}

__global__ __launch_bounds__(256) void scan3_kernel(
    int* __restrict__ offs, const int* __restrict__ bsum, int N, int E)
{
    int i = blockIdx.x * 256 + threadIdx.x;
    if (i < N) offs[i] += bsum[i >> 10];
    if (i == 0) offs[N] = E;
}

__global__ __launch_bounds__(256) void fill_kernel(
    const int* __restrict__ src, const int* __restrict__ dst,
    const int* __restrict__ offs, int* __restrict__ cursor,
    int* __restrict__ csr, int E)
{
    int e = blockIdx.x * 256 + threadIdx.x;
    if (e >= E) return;
    int d = dst[e];
    int p = atomicAdd(&cursor[d], 1);
    csr[offs[d] + p] = src[e];
}

// -------------------- gather aggregation: mean over in-neighbors -----------
__global__ __launch_bounds__(256) void agg_kernel(
    const float* __restrict__ h, const int* __restrict__ csr,
    const int* __restrict__ offs, float* __restrict__ mean, int N)
{
    int wid  = (blockIdx.x * 256 + threadIdx.x) >> 6;   // node id
    int lane = threadIdx.x & 63;
    if (wid >= N) return;
    int lo = offs[wid], hi = offs[wid + 1];
    float ax = 0.f, ay = 0.f;
    for (int base = lo; base < hi; base += 64) {
        int m = hi - base;
        int idx = 0;
        if (lane < m) idx = csr[base + lane];
        int cnt = m < 64 ? m : 64;
        int j = 0;
        for (; j + 3 < cnt; j += 4) {
            int s0 = __shfl(idx, j + 0);
            int s1 = __shfl(idx, j + 1);
            int s2 = __shfl(idx, j + 2);
            int s3 = __shfl(idx, j + 3);
            float2 v0 = *(const float2*)(h + (size_t)s0 * HID_F + lane * 2);
            float2 v1 = *(const float2*)(h + (size_t)s1 * HID_F + lane * 2);
            float2 v2 = *(const float2*)(h + (size_t)s2 * HID_F + lane * 2);
            float2 v3 = *(const float2*)(h + (size_t)s3 * HID_F + lane * 2);
            ax += v0.x + v1.x + v2.x + v3.x;
            ay += v0.y + v1.y + v2.y + v3.y;
        }
        for (; j < cnt; ++j) {
            int s0 = __shfl(idx, j);
            float2 v0 = *(const float2*)(h + (size_t)s0 * HID_F + lane * 2);
            ax += v0.x;
            ay += v0.y;
        }
    }
    float inv = (hi > lo) ? 1.0f / (float)(hi - lo) : 0.0f;
    float2 r;
    r.x = ax * inv;
    r.y = ay * inv;
    *(float2*)(mean + (size_t)wid * HID_F + lane * 2) = r;
}

// -------------------- SAGE update: z = h@Ws + mean@Wn + b + h; leaky -------
__global__ __launch_bounds__(256) void sage_kernel(
    const float* __restrict__ hin, const float* __restrict__ mean,
    const float* __restrict__ Ws, const float* __restrict__ Wn,
    const float* __restrict__ bias, float* __restrict__ hout, int N)
{
    __shared__ float s_h[32][HID_F];
    __shared__ float s_m[32][HID_F];
    int n0 = blockIdx.x * 32;
    for (int idx = threadIdx.x; idx < 32 * HID_F; idx += 256) {
        int nl = idx >> 7, i = idx & 127;
        int n = n0 + nl;
        float hv = 0.f, mv = 0.f;
        if (n < N) {
            hv = hin[(size_t)n * HID_F + i];
            mv = mean[(size_t)n * HID_F + i];
        }
        s_h[nl][i] = hv;
        s_m[nl][i] = mv;
    }
    __syncthreads();
    int og = threadIdx.x & 31;
    int ng = threadIdx.x >> 5;
    int o0 = og * 4, nl0 = ng * 4;
    float z[4][4] = {};
#pragma unroll 4
    for (int i = 0; i < HID_F; ++i) {
        float4 wsv = *(const float4*)(Ws + i * HID_F + o0);
        float4 wnv = *(const float4*)(Wn + i * HID_F + o0);
#pragma unroll
        for (int a = 0; a < 4; ++a) {
            float hv = s_h[nl0 + a][i];
            float mv = s_m[nl0 + a][i];
            z[a][0] = fmaf(hv, wsv.x, fmaf(mv, wnv.x, z[a][0]));
            z[a][1] = fmaf(hv, wsv.y, fmaf(mv, wnv.y, z[a][1]));
            z[a][2] = fmaf(hv, wsv.z, fmaf(mv, wnv.z, z[a][2]));
            z[a][3] = fmaf(hv, wsv.w, fmaf(mv, wnv.w, z[a][3]));
        }
    }
    float4 bv = *(const float4*)(bias + o0);
#pragma unroll
    for (int a = 0; a < 4; ++a) {
        int n = n0 + nl0 + a;
        if (n >= N) break;
        float4 r;
        r.x = z[a][0] + bv.x + s_h[nl0 + a][o0 + 0];
        r.y = z[a][1] + bv.y + s_h[nl0 + a][o0 + 1];
        r.z = z[a][2] + bv.z + s_h[nl0 + a][o0 + 2];
        r.w = z[a][3] + bv.w + s_h[nl0 + a][o0 + 3];
        r.x = r.x > 0.f ? r.x : 0.01f * r.x;
        r.y = r.y > 0.f ? r.y : 0.01f * r.y;
        r.z = r.z > 0.f ? r.z : 0.01f * r.z;
        r.w = r.w > 0.f ? r.w : 0.01f * r.w;
        *(float4*)(hout + (size_t)n * HID_F + o0) = r;
    }
}

// ------------- fused graph-mean pool + KAN readout layer 1 ------------------
__global__ __launch_bounds__(128) void pool_readout1_kernel(
    const float* __restrict__ h, const int* __restrict__ gid,
    const float* __restrict__ coefr1, const float* __restrict__ sbr1,
    const float* __restrict__ ssr1, float* __restrict__ ymid, int N)
{
    int g = blockIdx.x;
    int i = threadIdx.x;

    int lo = 0, hi = N;
    while (lo < hi) { int m = (lo + hi) >> 1; if (gid[m] < g) lo = m + 1; else hi = m; }
    int lo2 = lo, hi2 = N;
    while (lo2 < hi2) { int m = (lo2 + hi2) >> 1; if (gid[m] < g + 1) lo2 = m + 1; else hi2 = m; }

    float acc = 0.f;
    for (int n = lo; n < lo2; ++n) acc += h[(size_t)n * HID_F + i];
    float x = acc * (1.0f / fmaxf((float)(lo2 - lo), 1.0f));

    float B[NC];
    bspline11(x, B);
    float s = silu_f(x);
    const float* cp  = coefr1 + (size_t)i * (MID_F * NC);
    const float* ssp = ssr1 + (size_t)i * MID_F;
    const float* sbp = sbr1 + (size_t)i * MID_F;
    float p[MID_F];
#pragma unroll
    for (int o = 0; o < MID_F; ++o) {
        float t = 0.f;
#pragma unroll
        for (int c = 0; c < NC; ++c) t = fmaf(cp[o * NC + c], B[c], t);
        p[o] = sbp[o] * s + ssp[o] * t;
    }

#pragma unroll
    for (int off = 32; off >= 1; off >>= 1) {
#pragma unroll
        for (int o = 0; o < MID_F; ++o) p[o] += __shfl_down(p[o], off);
    }
    __shared__ float s_part[2][MID_F];
    int lane = threadIdx.x & 63, w = threadIdx.x >> 6;
    if (lane == 0) {
#pragma unroll
        for (int o = 0; o < MID_F; ++o) s_part[w][o] = p[o];
    }
    __syncthreads();
    if (threadIdx.x < MID_F)
        ymid[g * MID_F + threadIdx.x] = s_part[0][threadIdx.x] + s_part[1][threadIdx.x];
}

// -------------------- KAN readout layer 2 + sigmoid: [512,5] -> [512,1] ----
__global__ __launch_bounds__(256) void readout2_kernel(
    const float* __restrict__ ymid, const float* __restrict__ coefr2,
    const float* __restrict__ sbr2, const float* __restrict__ ssr2,
    float* __restrict__ out)
{
    int g = blockIdx.x * 256 + threadIdx.x;
    if (g >= NG) return;
    float acc = 0.f;
#pragma unroll
    for (int i = 0; i < MID_F; ++i) {
        float x = ymid[g * MID_F + i];
        float B[NC];
        bspline11(x, B);
        float t = 0.f;
#pragma unroll
        for (int c = 0; c < NC; ++c) t = fmaf(coefr2[i * NC + c], B[c], t);
        acc += sbr2[i] * silu_f(x) + ssr2[i] * t;
    }
    out[g] = 1.0f / (1.0f + expf(-acc));
}

// ---------------------------------------------------------------------------
extern "C" void kernel_launch(void* const* d_in, const int* in_sizes, int n_in,
                              void* d_out, int out_size, void* d_ws, size_t ws_size,
                              hipStream_t stream)
{
    const float* h     = (const float*)d_in[0];
    const int*   src   = (const int*)d_in[1];
    const int*   dst   = (const int*)d_in[2];
    const int*   gid   = (const int*)d_in[3];
    const float* coef1 = (const float*)d_in[4];
    const float* sb1   = (const float*)d_in[5];
    const float* ss1   = (const float*)d_in[6];
    const float* coef2 = (const float*)d_in[7];
    const float* sb2   = (const float*)d_in[8];
    const float* ss2   = (const float*)d_in[9];
    const float* Ws0   = (const float*)d_in[10];
    const float* Wn0   = (const float*)d_in[11];
    const float* b0    = (const float*)d_in[12];
    const float* Ws1   = (const float*)d_in[13];
    const float* Wn1   = (const float*)d_in[14];
    const float* b1    = (const float*)d_in[15];
    const float* coefr1= (const float*)d_in[16];
    const float* sbr1  = (const float*)d_in[17];
    const float* ssr1  = (const float*)d_in[18];
    const float* coefr2= (const float*)d_in[19];
    const float* sbr2  = (const float*)d_in[20];
    const float* ssr2  = (const float*)d_in[21];

    const int N = in_sizes[0] / IN_F;   // 100000
    const int E = in_sizes[1];          // 1600000

    // ---- workspace layout (identical footprint to round 4) ----
    float* ws   = (float*)d_ws;
    float* mid  = ws;                          // N*5
    float* h0   = mid + (size_t)N * MID_F;     // N*128
    float* h1   = h0 + (size_t)N * HID_F;      // N*128
    float* mean = h1 + (size_t)N * HID_F;      // N*128
    float* ymid = mean + (size_t)N * HID_F;    // 512*5
    int*   cnt  = (int*)(ymid + NG * MID_F);   // N   (reused as cursor)
    int*   offs = cnt + N;                     // N+1
    int*   bsum = offs + N + 1;                // 256
    int*   csr  = bsum + 256;                  // E

    // poly tables aliased onto `mean` (only needed before agg0 writes mean):
    // poly1 = 64*14*5*4 = 17920 floats, poly2 = 5*14*128*4 = 35840 floats
    float* poly1 = mean;
    float* poly2 = mean + IN_F * NJ * MID_F * 4;

    const int nblk = (N + 1023) / 1024;

    // build spline polynomial tables (ss folded in)
    build_poly1_kernel<<<(IN_F * NJ * MID_F + 255) / 256, 256, 0, stream>>>(coef1, ss1, poly1);
    build_poly2_kernel<<<(MID_F * NJ * HID_F + 255) / 256, 256, 0, stream>>>(coef2, ss2, poly2);

    // KAN encoder
    enc1_kernel<<<(N + 255) / 256, 256, 0, stream>>>(h, poly1, sb1, mid, N);
    enc2_kernel<<<2048, 256, 0, stream>>>(mid, poly2, sb2, h0, N);

    // CSR build (once; reused by both SAGE layers)
    hipMemsetAsync(cnt, 0, (size_t)N * sizeof(int), stream);
    count_kernel<<<(E + 255) / 256, 256, 0, stream>>>(dst, cnt, E);
    scan1_kernel<<<nblk, 256, 0, stream>>>(cnt, offs, bsum, N);
    scan2_kernel<<<1, 256, 0, stream>>>(bsum, nblk);
    scan3_kernel<<<(N + 255) / 256, 256, 0, stream>>>(offs, bsum, N, E);
    hipMemsetAsync(cnt, 0, (size_t)N * sizeof(int), stream);   // cnt -> cursor
    fill_kernel<<<(E + 255) / 256, 256, 0, stream>>>(src, dst, offs, cnt, csr, E);

    // SAGE layer 0
    agg_kernel<<<(N * 64 + 255) / 256, 256, 0, stream>>>(h0, csr, offs, mean, N);
    sage_kernel<<<(N + 31) / 32, 256, 0, stream>>>(h0, mean, Ws0, Wn0, b0, h1, N);

    // SAGE layer 1
    agg_kernel<<<(N * 64 + 255) / 256, 256, 0, stream>>>(h1, csr, offs, mean, N);
    sage_kernel<<<(N + 31) / 32, 256, 0, stream>>>(h1, mean, Ws1, Wn1, b1, h0, N);

    // fused pool + readout
    pool_readout1_kernel<<<NG, 128, 0, stream>>>(h0, gid, coefr1, sbr1, ssr1, ymid, N);
    readout2_kernel<<<2, 256, 0, stream>>>(ymid, coefr2, sbr2, ssr2, (float*)d_out);
}

// Round 6
// 767.327 us; speedup vs baseline: 8.2479x; 1.1683x over previous
//
#include <hip/hip_runtime.h>

// ---------------------------------------------------------------------------
// KAN-GNN forward on MI355X.  Sizes (fixed by reference): N=100000 nodes,
// E=1600000 edges, IN=64, MID=5, HID=128, OUT=1, NG=512 graphs, C=11 basis.
// Round 6: SAGE update -> bf16 MFMA.  z = [h|mean] @ [Ws;Wn] as one K=256
// GEMM on matrix cores (fp32 accum; residual/bias/leaky exact fp32).
// Weights repacked once per launch into fragment-ordered bf16 tables.
// ---------------------------------------------------------------------------

#define IN_F   64
#define MID_F  5
#define HID_F  128
#define NG     512
#define NC     11   // G_GRID + K_SPLINE = 8 + 3
#define NJ     14   // intervals of [-1.75, 1.75) at h=0.25

typedef __attribute__((ext_vector_type(8))) __bf16 bf16x8;
typedef __attribute__((ext_vector_type(4))) float  f32x4;

// Cubic B-spline basis on uniform knots t_j = -1.75 + 0.25 j, j=0..14.
// (used by the tiny readout kernels)
__device__ __forceinline__ void bspline11(float x, float* __restrict__ B) {
    float b[14];
#pragma unroll
    for (int j = 0; j < 14; ++j) {
        float tj = -1.75f + 0.25f * j;
        b[j] = (x >= tj && x < tj + 0.25f) ? 1.0f : 0.0f;
    }
#pragma unroll
    for (int d = 1; d <= 3; ++d) {
        float inv = 1.0f / (0.25f * d);
#pragma unroll 14
        for (int j = 0; j < 14 - 3; ++j) {
            if (j < 14 - d) {
                float tj   = -1.75f + 0.25f * j;
                float tjd1 = tj + 0.25f * (d + 1);
                b[j] = ((x - tj) * b[j] + (tjd1 - x) * b[j + 1]) * inv;
            }
        }
        if (d < 3) {
#pragma unroll
            for (int j = 11; j < 14; ++j) {
                if (j < 14 - d) {
                    float tj   = -1.75f + 0.25f * j;
                    float tjd1 = tj + 0.25f * (d + 1);
                    b[j] = ((x - tj) * b[j] + (tjd1 - x) * b[j + 1]) * inv;
                }
            }
        }
    }
#pragma unroll
    for (int j = 0; j < NC; ++j) B[j] = b[j];
}

__device__ __forceinline__ float silu_f(float x) { return x / (1.0f + expf(-x)); }

// ---- build piecewise-cubic tables: poly[idx][4] = {a,b,c,d} in local u ----
__device__ __forceinline__ float4 poly_from_coefs(float c0, float c1, float c2, float c3) {
    const float s = 1.0f / 6.0f;
    float4 p;
    p.x = (-c0 + 3.f*c1 - 3.f*c2 + c3) * s;   // u^3
    p.y = ( 3.f*c0 - 6.f*c1 + 3.f*c2) * s;    // u^2
    p.z = (-3.f*c0 + 3.f*c2) * s;             // u^1
    p.w = (      c0 + 4.f*c1 + c2) * s;       // 1
    return p;
}

// poly1 layout: [i (64)][j (14)][o (5)][4]
__global__ __launch_bounds__(256) void build_poly1_kernel(
    const float* __restrict__ coef1, const float* __restrict__ ss1,
    float* __restrict__ poly1)
{
    int idx = blockIdx.x * 256 + threadIdx.x;
    if (idx >= IN_F * NJ * MID_F) return;
    int o = idx % MID_F;
    int t = idx / MID_F;
    int j = t % NJ;
    int i = t / NJ;
    float ss = ss1[i * MID_F + o];
    float c[4];
#pragma unroll
    for (int k = 0; k < 4; ++k) {
        int cc = j - 3 + k;
        c[k] = (cc >= 0 && cc <= 10) ? coef1[(i * MID_F + o) * NC + cc] * ss : 0.f;
    }
    *(float4*)(poly1 + (size_t)idx * 4) = poly_from_coefs(c[0], c[1], c[2], c[3]);
}

// poly2 layout: [i (5)][j (14)][o (128)][4]
__global__ __launch_bounds__(256) void build_poly2_kernel(
    const float* __restrict__ coef2, const float* __restrict__ ss2,
    float* __restrict__ poly2)
{
    int idx = blockIdx.x * 256 + threadIdx.x;
    if (idx >= MID_F * NJ * HID_F) return;
    int o = idx & 127;
    int t = idx >> 7;
    int j = t % NJ;
    int i = t / NJ;
    float ss = ss2[i * HID_F + o];
    float c[4];
#pragma unroll
    for (int k = 0; k < 4; ++k) {
        int cc = j - 3 + k;
        c[k] = (cc >= 0 && cc <= 10) ? coef2[(i * HID_F + o) * NC + cc] * ss : 0.f;
    }
    *(float4*)(poly2 + (size_t)idx * 4) = poly_from_coefs(c[0], c[1], c[2], c[3]);
}

// ---- repack [Ws;Wn] (K=256 x 128) into MFMA fragment order, bf16 ----------
// dst ushort index: ((ks*8 + c)*64 + l)*8 + j  where k = ks*32 + (l>>4)*8 + j,
// col = c*16 + (l&15).  One thread per (k,col) element; both layers.
__global__ __launch_bounds__(256) void build_wfrag_kernel(
    const float* __restrict__ Ws0, const float* __restrict__ Wn0,
    const float* __restrict__ Ws1, const float* __restrict__ Wn1,
    unsigned short* __restrict__ wfrag0, unsigned short* __restrict__ wfrag1)
{
    int t = blockIdx.x * 256 + threadIdx.x;
    if (t >= 2 * 256 * HID_F) return;
    int layer = t >> 15;
    int e = t & 32767;
    int col = e & 127;
    int k   = e >> 7;          // 0..255
    int ks  = k >> 5;
    int kin = k & 31;
    int lg  = kin >> 3;
    int j   = kin & 7;
    int c   = col >> 4;
    int li  = col & 15;
    int l   = lg * 16 + li;
    const float* Ws = layer ? Ws1 : Ws0;
    const float* Wn = layer ? Wn1 : Wn0;
    float v = (k < HID_F) ? Ws[k * HID_F + col] : Wn[(k - HID_F) * HID_F + col];
    unsigned short us = __builtin_bit_cast(unsigned short, (__bf16)v);
    unsigned short* dst = layer ? wfrag1 : wfrag0;
    dst[((ks * 8 + c) * 64 + l) * 8 + j] = us;
}

// -------------------- KAN encoder layer 1: [N,64] -> [N,5] -----------------
__global__ __launch_bounds__(256) void enc1_kernel(
    const float* __restrict__ h, const float* __restrict__ poly1,
    const float* __restrict__ sb1, float* __restrict__ mid, int N)
{
    __shared__ float s_sb[IN_F * MID_F];
    for (int idx = threadIdx.x; idx < IN_F * MID_F; idx += 256)
        s_sb[idx] = sb1[idx];
    __syncthreads();

    int n = blockIdx.x * 256 + threadIdx.x;
    if (n >= N) return;
    const float* hr = h + (size_t)n * IN_F;
    float acc[MID_F] = {0, 0, 0, 0, 0};

#pragma unroll 4
    for (int i4 = 0; i4 < IN_F; i4 += 4) {
        float4 xv = *(const float4*)(hr + i4);
        float xs[4] = {xv.x, xv.y, xv.z, xv.w};
#pragma unroll
        for (int k = 0; k < 4; ++k) {
            int i = i4 + k;
            float x = xs[k];
            float xf = (x + 1.75f) * 4.0f;
            float fj = floorf(xf);
            int j0 = (int)fj;
            j0 = j0 < 0 ? 0 : (j0 > 13 ? 13 : j0);
            float u = xf - fj;
            float msk = (x >= -1.75f && x < 1.75f) ? 1.0f : 0.0f;
            float s = silu_f(x);
            const float* pp = poly1 + ((size_t)(i * NJ + j0) * MID_F) * 4;
#pragma unroll
            for (int o = 0; o < MID_F; ++o) {
                float4 p = *(const float4*)(pp + 4 * o);
                float t = fmaf(fmaf(fmaf(p.x, u, p.y), u, p.z), u, p.w);
                acc[o] = fmaf(s_sb[i * MID_F + o], s, acc[o]);
                acc[o] = fmaf(t, msk, acc[o]);
            }
        }
    }
#pragma unroll
    for (int o = 0; o < MID_F; ++o) mid[(size_t)n * MID_F + o] = acc[o];
}

// -------------------- KAN encoder layer 2: [N,5] -> [N,128] ----------------
__global__ __launch_bounds__(256) void enc2_kernel(
    const float* __restrict__ mid, const float* __restrict__ poly2,
    const float* __restrict__ sb2, float* __restrict__ h0, int N)
{
    __shared__ float s_u[2][MID_F], s_sil[2][MID_F], s_msk[2][MID_F];
    __shared__ int   s_j0[2][MID_F];
    int o  = threadIdx.x & 127;
    int ln = threadIdx.x >> 7;

    float sbr[MID_F];
#pragma unroll
    for (int i = 0; i < MID_F; ++i) sbr[i] = sb2[i * HID_F + o];

    int nTiles = (N + 1) / 2;
    for (int tile = blockIdx.x; tile < nTiles; tile += gridDim.x) {
        __syncthreads();
        if (threadIdx.x < 2 * MID_F) {
            int l = threadIdx.x / MID_F, i = threadIdx.x % MID_F;
            int n = tile * 2 + l;
            float x = (n < N) ? mid[(size_t)n * MID_F + i] : 0.f;
            float xf = (x + 1.75f) * 4.0f;
            float fj = floorf(xf);
            int j0 = (int)fj;
            j0 = j0 < 0 ? 0 : (j0 > 13 ? 13 : j0);
            s_j0[l][i]  = j0;
            s_u[l][i]   = xf - fj;
            s_msk[l][i] = (x >= -1.75f && x < 1.75f) ? 1.0f : 0.0f;
            s_sil[l][i] = silu_f(x);
        }
        __syncthreads();
        int n = tile * 2 + ln;
        if (n < N) {
            float z = 0.f;
#pragma unroll
            for (int i = 0; i < MID_F; ++i) {
                float4 p = *(const float4*)(poly2 +
                            ((size_t)((i * NJ + s_j0[ln][i]) * HID_F + o)) * 4);
                float u = s_u[ln][i];
                float t = fmaf(fmaf(fmaf(p.x, u, p.y), u, p.z), u, p.w);
                z = fmaf(sbr[i], s_sil[ln][i], z);
                z = fmaf(t, s_msk[ln][i], z);
            }
            h0[(size_t)n * HID_F + o] = z;
        }
    }
}

// -------------------- CSR build: count / scan / fill -----------------------
__global__ __launch_bounds__(256) void count_kernel(
    const int* __restrict__ dst, int* __restrict__ cnt, int E)
{
    int e = blockIdx.x * 256 + threadIdx.x;
    if (e < E) atomicAdd(&cnt[dst[e]], 1);
}

__global__ __launch_bounds__(256) void scan1_kernel(
    const int* __restrict__ cnt, int* __restrict__ offs,
    int* __restrict__ bsum, int N)
{
    __shared__ int s[256];
    int base = blockIdx.x * 1024 + threadIdx.x * 4;
    int v0 = (base + 0 < N) ? cnt[base + 0] : 0;
    int v1 = (base + 1 < N) ? cnt[base + 1] : 0;
    int v2 = (base + 2 < N) ? cnt[base + 2] : 0;
    int v3 = (base + 3 < N) ? cnt[base + 3] : 0;
    int tsum = v0 + v1 + v2 + v3;
    s[threadIdx.x] = tsum;
    __syncthreads();
    for (int off = 1; off < 256; off <<= 1) {
        int t = 0;
        if (threadIdx.x >= off) t = s[threadIdx.x - off];
        __syncthreads();
        if (threadIdx.x >= off) s[threadIdx.x] += t;
        __syncthreads();
    }
    int p = s[threadIdx.x] - tsum;
    if (threadIdx.x == 255) bsum[blockIdx.x] = s[255];
    if (base + 0 < N) { offs[base + 0] = p; p += v0; }
    if (base + 1 < N) { offs[base + 1] = p; p += v1; }
    if (base + 2 < N) { offs[base + 2] = p; p += v2; }
    if (base + 3 < N) { offs[base + 3] = p; p += v3; }
}

__global__ __launch_bounds__(256) void scan2_kernel(int* __restrict__ bsum, int nblk)
{
    __shared__ int s[256];
    int v = (threadIdx.x < nblk) ? bsum[threadIdx.x] : 0;
    s[threadIdx.x] = v;
    __syncthreads();
    for (int off = 1; off < 256; off <<= 1) {
        int t = 0;
        if (threadIdx.x >= off) t = s[threadIdx.x - off];
        __syncthreads();
        if (threadIdx.x >= off) s[threadIdx.x] += t;
        __syncthreads();
    }
    if (threadIdx.x < nblk) bsum[threadIdx.x] = s[threadIdx.x] - v;
}

__global__ __launch_bounds__(256) void scan3_kernel(
    int* __restrict__ offs, const int* __restrict__ bsum, int N, int E)
{
    int i = blockIdx.x * 256 + threadIdx.x;
    if (i < N) offs[i] += bsum[i >> 10];
    if (i == 0) offs[N] = E;
}

__global__ __launch_bounds__(256) void fill_kernel(
    const int* __restrict__ src, const int* __restrict__ dst,
    const int* __restrict__ offs, int* __restrict__ cursor,
    int* __restrict__ csr, int E)
{
    int e = blockIdx.x * 256 + threadIdx.x;
    if (e >= E) return;
    int d = dst[e];
    int p = atomicAdd(&cursor[d], 1);
    csr[offs[d] + p] = src[e];
}

// -------------------- gather aggregation: mean over in-neighbors -----------
__global__ __launch_bounds__(256) void agg_kernel(
    const float* __restrict__ h, const int* __restrict__ csr,
    const int* __restrict__ offs, float* __restrict__ mean, int N)
{
    int wid  = (blockIdx.x * 256 + threadIdx.x) >> 6;   // node id
    int lane = threadIdx.x & 63;
    if (wid >= N) return;
    int lo = offs[wid], hi = offs[wid + 1];
    float ax = 0.f, ay = 0.f;
    for (int base = lo; base < hi; base += 64) {
        int m = hi - base;
        int idx = 0;
        if (lane < m) idx = csr[base + lane];
        int cnt = m < 64 ? m : 64;
        int j = 0;
        for (; j + 3 < cnt; j += 4) {
            int s0 = __shfl(idx, j + 0);
            int s1 = __shfl(idx, j + 1);
            int s2 = __shfl(idx, j + 2);
            int s3 = __shfl(idx, j + 3);
            float2 v0 = *(const float2*)(h + (size_t)s0 * HID_F + lane * 2);
            float2 v1 = *(const float2*)(h + (size_t)s1 * HID_F + lane * 2);
            float2 v2 = *(const float2*)(h + (size_t)s2 * HID_F + lane * 2);
            float2 v3 = *(const float2*)(h + (size_t)s3 * HID_F + lane * 2);
            ax += v0.x + v1.x + v2.x + v3.x;
            ay += v0.y + v1.y + v2.y + v3.y;
        }
        for (; j < cnt; ++j) {
            int s0 = __shfl(idx, j);
            float2 v0 = *(const float2*)(h + (size_t)s0 * HID_F + lane * 2);
            ax += v0.x;
            ay += v0.y;
        }
    }
    float inv = (hi > lo) ? 1.0f / (float)(hi - lo) : 0.0f;
    float2 r;
    r.x = ax * inv;
    r.y = ay * inv;
    *(float2*)(mean + (size_t)wid * HID_F + lane * 2) = r;
}

// -------------------- SAGE update via MFMA ---------------------------------
// z = [h|mean](bf16) @ wfrag(bf16, K=256) + bias + h (fp32); leaky-relu.
// Block = 256 threads = 4 waves; wave w owns nodes [blk*64 + w*16, +16),
// all 128 output cols (8 coltile fragments).  LDS-free.
__global__ __launch_bounds__(256) void sage_mfma_kernel(
    const float* __restrict__ hin, const float* __restrict__ mean,
    const unsigned short* __restrict__ wfrag, const float* __restrict__ bias,
    float* __restrict__ hout, int N)
{
    int wv = threadIdx.x >> 6;
    int l  = threadIdx.x & 63;
    int n0 = blockIdx.x * 64 + wv * 16;
    int r  = l & 15;
    int kg = l >> 4;                          // 0..3

    const float* aph = hin  + (size_t)(n0 + r) * HID_F + kg * 8;
    const float* apm = mean + (size_t)(n0 + r) * HID_F + kg * 8;
    const uint4* wp  = (const uint4*)wfrag + l;

    f32x4 acc[8] = {};
#pragma unroll
    for (int ks = 0; ks < 8; ++ks) {
        const float* ap = (ks < 4) ? (aph + ks * 32) : (apm + (ks - 4) * 32);
        float4 a0 = *(const float4*)ap;
        float4 a1 = *(const float4*)(ap + 4);
        bf16x8 a;
        a[0] = (__bf16)a0.x; a[1] = (__bf16)a0.y;
        a[2] = (__bf16)a0.z; a[3] = (__bf16)a0.w;
        a[4] = (__bf16)a1.x; a[5] = (__bf16)a1.y;
        a[6] = (__bf16)a1.z; a[7] = (__bf16)a1.w;
#pragma unroll
        for (int c = 0; c < 8; ++c) {
            uint4 w = wp[(ks * 8 + c) * 64];
            bf16x8 b = __builtin_bit_cast(bf16x8, w);
            acc[c] = __builtin_amdgcn_mfma_f32_16x16x32_bf16(a, b, acc[c], 0, 0, 0);
        }
    }

    // epilogue: D[row=(l>>4)*4+rr][col=c*16+(l&15)]
    int row0 = kg * 4;
#pragma unroll
    for (int c = 0; c < 8; ++c) {
        int col = c * 16 + r;
        float bv = bias[col];
#pragma unroll
        for (int rr = 0; rr < 4; ++rr) {
            int grow = n0 + row0 + rr;
            if (grow < N) {
                float z = acc[c][rr] + bv + hin[(size_t)grow * HID_F + col];
                z = z > 0.f ? z : 0.01f * z;
                hout[(size_t)grow * HID_F + col] = z;
            }
        }
    }
}

// ------------- fused graph-mean pool + KAN readout layer 1 ------------------
__global__ __launch_bounds__(128) void pool_readout1_kernel(
    const float* __restrict__ h, const int* __restrict__ gid,
    const float* __restrict__ coefr1, const float* __restrict__ sbr1,
    const float* __restrict__ ssr1, float* __restrict__ ymid, int N)
{
    int g = blockIdx.x;
    int i = threadIdx.x;

    int lo = 0, hi = N;
    while (lo < hi) { int m = (lo + hi) >> 1; if (gid[m] < g) lo = m + 1; else hi = m; }
    int lo2 = lo, hi2 = N;
    while (lo2 < hi2) { int m = (lo2 + hi2) >> 1; if (gid[m] < g + 1) lo2 = m + 1; else hi2 = m; }

    float acc = 0.f;
    for (int n = lo; n < lo2; ++n) acc += h[(size_t)n * HID_F + i];
    float x = acc * (1.0f / fmaxf((float)(lo2 - lo), 1.0f));

    float B[NC];
    bspline11(x, B);
    float s = silu_f(x);
    const float* cp  = coefr1 + (size_t)i * (MID_F * NC);
    const float* ssp = ssr1 + (size_t)i * MID_F;
    const float* sbp = sbr1 + (size_t)i * MID_F;
    float p[MID_F];
#pragma unroll
    for (int o = 0; o < MID_F; ++o) {
        float t = 0.f;
#pragma unroll
        for (int c = 0; c < NC; ++c) t = fmaf(cp[o * NC + c], B[c], t);
        p[o] = sbp[o] * s + ssp[o] * t;
    }

#pragma unroll
    for (int off = 32; off >= 1; off >>= 1) {
#pragma unroll
        for (int o = 0; o < MID_F; ++o) p[o] += __shfl_down(p[o], off);
    }
    __shared__ float s_part[2][MID_F];
    int lane = threadIdx.x & 63, w = threadIdx.x >> 6;
    if (lane == 0) {
#pragma unroll
        for (int o = 0; o < MID_F; ++o) s_part[w][o] = p[o];
    }
    __syncthreads();
    if (threadIdx.x < MID_F)
        ymid[g * MID_F + threadIdx.x] = s_part[0][threadIdx.x] + s_part[1][threadIdx.x];
}

// -------------------- KAN readout layer 2 + sigmoid: [512,5] -> [512,1] ----
__global__ __launch_bounds__(256) void readout2_kernel(
    const float* __restrict__ ymid, const float* __restrict__ coefr2,
    const float* __restrict__ sbr2, const float* __restrict__ ssr2,
    float* __restrict__ out)
{
    int g = blockIdx.x * 256 + threadIdx.x;
    if (g >= NG) return;
    float acc = 0.f;
#pragma unroll
    for (int i = 0; i < MID_F; ++i) {
        float x = ymid[g * MID_F + i];
        float B[NC];
        bspline11(x, B);
        float t = 0.f;
#pragma unroll
        for (int c = 0; c < NC; ++c) t = fmaf(coefr2[i * NC + c], B[c], t);
        acc += sbr2[i] * silu_f(x) + ssr2[i] * t;
    }
    out[g] = 1.0f / (1.0f + expf(-acc));
}

// ---------------------------------------------------------------------------
extern "C" void kernel_launch(void* const* d_in, const int* in_sizes, int n_in,
                              void* d_out, int out_size, void* d_ws, size_t ws_size,
                              hipStream_t stream)
{
    const float* h     = (const float*)d_in[0];
    const int*   src   = (const int*)d_in[1];
    const int*   dst   = (const int*)d_in[2];
    const int*   gid   = (const int*)d_in[3];
    const float* coef1 = (const float*)d_in[4];
    const float* sb1   = (const float*)d_in[5];
    const float* ss1   = (const float*)d_in[6];
    const float* coef2 = (const float*)d_in[7];
    const float* sb2   = (const float*)d_in[8];
    const float* ss2   = (const float*)d_in[9];
    const float* Ws0   = (const float*)d_in[10];
    const float* Wn0   = (const float*)d_in[11];
    const float* b0    = (const float*)d_in[12];
    const float* Ws1   = (const float*)d_in[13];
    const float* Wn1   = (const float*)d_in[14];
    const float* b1    = (const float*)d_in[15];
    const float* coefr1= (const float*)d_in[16];
    const float* sbr1  = (const float*)d_in[17];
    const float* ssr1  = (const float*)d_in[18];
    const float* coefr2= (const float*)d_in[19];
    const float* sbr2  = (const float*)d_in[20];
    const float* ssr2  = (const float*)d_in[21];

    const int N = in_sizes[0] / IN_F;   // 100000
    const int E = in_sizes[1];          // 1600000

    // ---- workspace layout ----
    float* ws   = (float*)d_ws;
    float* mid  = ws;                                   // N*5
    float* h0   = mid + (size_t)N * MID_F;              // N*128
    float* h1   = h0 + (size_t)N * HID_F;               // N*128
    float* mean = h1 + (size_t)N * HID_F;               // N*128
    float* ymid = mean + (size_t)N * HID_F;             // 512*5  (mult of 4)
    unsigned short* wfrag0 = (unsigned short*)(ymid + NG * MID_F);  // 32768 us
    unsigned short* wfrag1 = wfrag0 + 32768;                        // 32768 us
    int*   cnt  = (int*)(wfrag1 + 32768);               // N (reused as cursor)
    int*   offs = cnt + N;                              // N+1
    int*   bsum = offs + N + 1;                         // 256
    int*   csr  = bsum + 256;                           // E

    // poly tables aliased onto `mean` (dead until agg0 writes mean):
    float* poly1 = mean;                                // 64*14*5*4  = 17920
    float* poly2 = mean + IN_F * NJ * MID_F * 4;        // 5*14*128*4 = 35840

    const int nblk = (N + 1023) / 1024;

    // build spline polynomial tables + bf16 weight fragment tables
    build_poly1_kernel<<<(IN_F * NJ * MID_F + 255) / 256, 256, 0, stream>>>(coef1, ss1, poly1);
    build_poly2_kernel<<<(MID_F * NJ * HID_F + 255) / 256, 256, 0, stream>>>(coef2, ss2, poly2);
    build_wfrag_kernel<<<(2 * 256 * HID_F + 255) / 256, 256, 0, stream>>>(
        Ws0, Wn0, Ws1, Wn1, wfrag0, wfrag1);

    // KAN encoder
    enc1_kernel<<<(N + 255) / 256, 256, 0, stream>>>(h, poly1, sb1, mid, N);
    enc2_kernel<<<2048, 256, 0, stream>>>(mid, poly2, sb2, h0, N);

    // CSR build (once; reused by both SAGE layers)
    hipMemsetAsync(cnt, 0, (size_t)N * sizeof(int), stream);
    count_kernel<<<(E + 255) / 256, 256, 0, stream>>>(dst, cnt, E);
    scan1_kernel<<<nblk, 256, 0, stream>>>(cnt, offs, bsum, N);
    scan2_kernel<<<1, 256, 0, stream>>>(bsum, nblk);
    scan3_kernel<<<(N + 255) / 256, 256, 0, stream>>>(offs, bsum, N, E);
    hipMemsetAsync(cnt, 0, (size_t)N * sizeof(int), stream);   // cnt -> cursor
    fill_kernel<<<(E + 255) / 256, 256, 0, stream>>>(src, dst, offs, cnt, csr, E);

    // SAGE layer 0
    agg_kernel<<<(N * 64 + 255) / 256, 256, 0, stream>>>(h0, csr, offs, mean, N);
    sage_mfma_kernel<<<(N + 63) / 64, 256, 0, stream>>>(h0, mean, wfrag0, b0, h1, N);

    // SAGE layer 1
    agg_kernel<<<(N * 64 + 255) / 256, 256, 0, stream>>>(h1, csr, offs, mean, N);
    sage_mfma_kernel<<<(N + 63) / 64, 256, 0, stream>>>(h1, mean, wfrag1, b1, h0, N);

    // fused pool + readout
    pool_readout1_kernel<<<NG, 128, 0, stream>>>(h0, gid, coefr1, sbr1, ssr1, ymid, N);
    readout2_kernel<<<2, 256, 0, stream>>>(ymid, coefr2, sbr2, ssr2, (float*)d_out);
}

// Round 7
// 672.391 us; speedup vs baseline: 9.4125x; 1.1412x over previous
//
#include <hip/hip_runtime.h>

// ---------------------------------------------------------------------------
// KAN-GNN forward on MI355X.  Sizes (fixed by reference): N=100000 nodes,
// E=1600000 edges, IN=64, MID=5, HID=128, OUT=1, NG=512 graphs, C=11 basis.
// Round 7: bf16 gather path.  h carries a bf16 shadow (hb); agg gathers
// 256B bf16 rows (was 512B fp32) and writes mean directly as bf16 (meanb);
// sage loads MFMA A-fragments as raw 16B uint4 from hb/meanb.  Residual,
// bias, leaky, pool, readout all stay exact fp32.
// ---------------------------------------------------------------------------

#define IN_F   64
#define MID_F  5
#define HID_F  128
#define NG     512
#define NC     11   // G_GRID + K_SPLINE = 8 + 3
#define NJ     14   // intervals of [-1.75, 1.75) at h=0.25

typedef __attribute__((ext_vector_type(8))) __bf16 bf16x8;
typedef __attribute__((ext_vector_type(4))) float  f32x4;

// Cubic B-spline basis on uniform knots t_j = -1.75 + 0.25 j, j=0..14.
// (used by the tiny readout kernels)
__device__ __forceinline__ void bspline11(float x, float* __restrict__ B) {
    float b[14];
#pragma unroll
    for (int j = 0; j < 14; ++j) {
        float tj = -1.75f + 0.25f * j;
        b[j] = (x >= tj && x < tj + 0.25f) ? 1.0f : 0.0f;
    }
#pragma unroll
    for (int d = 1; d <= 3; ++d) {
        float inv = 1.0f / (0.25f * d);
#pragma unroll 14
        for (int j = 0; j < 14 - 3; ++j) {
            if (j < 14 - d) {
                float tj   = -1.75f + 0.25f * j;
                float tjd1 = tj + 0.25f * (d + 1);
                b[j] = ((x - tj) * b[j] + (tjd1 - x) * b[j + 1]) * inv;
            }
        }
        if (d < 3) {
#pragma unroll
            for (int j = 11; j < 14; ++j) {
                if (j < 14 - d) {
                    float tj   = -1.75f + 0.25f * j;
                    float tjd1 = tj + 0.25f * (d + 1);
                    b[j] = ((x - tj) * b[j] + (tjd1 - x) * b[j + 1]) * inv;
                }
            }
        }
    }
#pragma unroll
    for (int j = 0; j < NC; ++j) B[j] = b[j];
}

__device__ __forceinline__ float silu_f(float x) { return x / (1.0f + expf(-x)); }

// ---- build piecewise-cubic tables: poly[idx][4] = {a,b,c,d} in local u ----
__device__ __forceinline__ float4 poly_from_coefs(float c0, float c1, float c2, float c3) {
    const float s = 1.0f / 6.0f;
    float4 p;
    p.x = (-c0 + 3.f*c1 - 3.f*c2 + c3) * s;   // u^3
    p.y = ( 3.f*c0 - 6.f*c1 + 3.f*c2) * s;    // u^2
    p.z = (-3.f*c0 + 3.f*c2) * s;             // u^1
    p.w = (      c0 + 4.f*c1 + c2) * s;       // 1
    return p;
}

// poly1 layout: [i (64)][j (14)][o (5)][4]
__global__ __launch_bounds__(256) void build_poly1_kernel(
    const float* __restrict__ coef1, const float* __restrict__ ss1,
    float* __restrict__ poly1)
{
    int idx = blockIdx.x * 256 + threadIdx.x;
    if (idx >= IN_F * NJ * MID_F) return;
    int o = idx % MID_F;
    int t = idx / MID_F;
    int j = t % NJ;
    int i = t / NJ;
    float ss = ss1[i * MID_F + o];
    float c[4];
#pragma unroll
    for (int k = 0; k < 4; ++k) {
        int cc = j - 3 + k;
        c[k] = (cc >= 0 && cc <= 10) ? coef1[(i * MID_F + o) * NC + cc] * ss : 0.f;
    }
    *(float4*)(poly1 + (size_t)idx * 4) = poly_from_coefs(c[0], c[1], c[2], c[3]);
}

// poly2 layout: [i (5)][j (14)][o (128)][4]
__global__ __launch_bounds__(256) void build_poly2_kernel(
    const float* __restrict__ coef2, const float* __restrict__ ss2,
    float* __restrict__ poly2)
{
    int idx = blockIdx.x * 256 + threadIdx.x;
    if (idx >= MID_F * NJ * HID_F) return;
    int o = idx & 127;
    int t = idx >> 7;
    int j = t % NJ;
    int i = t / NJ;
    float ss = ss2[i * HID_F + o];
    float c[4];
#pragma unroll
    for (int k = 0; k < 4; ++k) {
        int cc = j - 3 + k;
        c[k] = (cc >= 0 && cc <= 10) ? coef2[(i * HID_F + o) * NC + cc] * ss : 0.f;
    }
    *(float4*)(poly2 + (size_t)idx * 4) = poly_from_coefs(c[0], c[1], c[2], c[3]);
}

// ---- repack [Ws;Wn] (K=256 x 128) into MFMA fragment order, bf16 ----------
__global__ __launch_bounds__(256) void build_wfrag_kernel(
    const float* __restrict__ Ws0, const float* __restrict__ Wn0,
    const float* __restrict__ Ws1, const float* __restrict__ Wn1,
    unsigned short* __restrict__ wfrag0, unsigned short* __restrict__ wfrag1)
{
    int t = blockIdx.x * 256 + threadIdx.x;
    if (t >= 2 * 256 * HID_F) return;
    int layer = t >> 15;
    int e = t & 32767;
    int col = e & 127;
    int k   = e >> 7;          // 0..255
    int ks  = k >> 5;
    int kin = k & 31;
    int lg  = kin >> 3;
    int j   = kin & 7;
    int c   = col >> 4;
    int li  = col & 15;
    int l   = lg * 16 + li;
    const float* Ws = layer ? Ws1 : Ws0;
    const float* Wn = layer ? Wn1 : Wn0;
    float v = (k < HID_F) ? Ws[k * HID_F + col] : Wn[(k - HID_F) * HID_F + col];
    unsigned short us = __builtin_bit_cast(unsigned short, (__bf16)v);
    unsigned short* dst = layer ? wfrag1 : wfrag0;
    dst[((ks * 8 + c) * 64 + l) * 8 + j] = us;
}

// -------------------- KAN encoder layer 1: [N,64] -> [N,5] -----------------
__global__ __launch_bounds__(256) void enc1_kernel(
    const float* __restrict__ h, const float* __restrict__ poly1,
    const float* __restrict__ sb1, float* __restrict__ mid, int N)
{
    __shared__ float s_sb[IN_F * MID_F];
    for (int idx = threadIdx.x; idx < IN_F * MID_F; idx += 256)
        s_sb[idx] = sb1[idx];
    __syncthreads();

    int n = blockIdx.x * 256 + threadIdx.x;
    if (n >= N) return;
    const float* hr = h + (size_t)n * IN_F;
    float acc[MID_F] = {0, 0, 0, 0, 0};

#pragma unroll 4
    for (int i4 = 0; i4 < IN_F; i4 += 4) {
        float4 xv = *(const float4*)(hr + i4);
        float xs[4] = {xv.x, xv.y, xv.z, xv.w};
#pragma unroll
        for (int k = 0; k < 4; ++k) {
            int i = i4 + k;
            float x = xs[k];
            float xf = (x + 1.75f) * 4.0f;
            float fj = floorf(xf);
            int j0 = (int)fj;
            j0 = j0 < 0 ? 0 : (j0 > 13 ? 13 : j0);
            float u = xf - fj;
            float msk = (x >= -1.75f && x < 1.75f) ? 1.0f : 0.0f;
            float s = silu_f(x);
            const float* pp = poly1 + ((size_t)(i * NJ + j0) * MID_F) * 4;
#pragma unroll
            for (int o = 0; o < MID_F; ++o) {
                float4 p = *(const float4*)(pp + 4 * o);
                float t = fmaf(fmaf(fmaf(p.x, u, p.y), u, p.z), u, p.w);
                acc[o] = fmaf(s_sb[i * MID_F + o], s, acc[o]);
                acc[o] = fmaf(t, msk, acc[o]);
            }
        }
    }
#pragma unroll
    for (int o = 0; o < MID_F; ++o) mid[(size_t)n * MID_F + o] = acc[o];
}

// ------------- KAN encoder layer 2: [N,5] -> [N,128] (+ bf16 shadow) -------
__global__ __launch_bounds__(256) void enc2_kernel(
    const float* __restrict__ mid, const float* __restrict__ poly2,
    const float* __restrict__ sb2, float* __restrict__ h0,
    unsigned short* __restrict__ hb, int N)
{
    __shared__ float s_u[2][MID_F], s_sil[2][MID_F], s_msk[2][MID_F];
    __shared__ int   s_j0[2][MID_F];
    int o  = threadIdx.x & 127;
    int ln = threadIdx.x >> 7;

    float sbr[MID_F];
#pragma unroll
    for (int i = 0; i < MID_F; ++i) sbr[i] = sb2[i * HID_F + o];

    int nTiles = (N + 1) / 2;
    for (int tile = blockIdx.x; tile < nTiles; tile += gridDim.x) {
        __syncthreads();
        if (threadIdx.x < 2 * MID_F) {
            int l = threadIdx.x / MID_F, i = threadIdx.x % MID_F;
            int n = tile * 2 + l;
            float x = (n < N) ? mid[(size_t)n * MID_F + i] : 0.f;
            float xf = (x + 1.75f) * 4.0f;
            float fj = floorf(xf);
            int j0 = (int)fj;
            j0 = j0 < 0 ? 0 : (j0 > 13 ? 13 : j0);
            s_j0[l][i]  = j0;
            s_u[l][i]   = xf - fj;
            s_msk[l][i] = (x >= -1.75f && x < 1.75f) ? 1.0f : 0.0f;
            s_sil[l][i] = silu_f(x);
        }
        __syncthreads();
        int n = tile * 2 + ln;
        if (n < N) {
            float z = 0.f;
#pragma unroll
            for (int i = 0; i < MID_F; ++i) {
                float4 p = *(const float4*)(poly2 +
                            ((size_t)((i * NJ + s_j0[ln][i]) * HID_F + o)) * 4);
                float u = s_u[ln][i];
                float t = fmaf(fmaf(fmaf(p.x, u, p.y), u, p.z), u, p.w);
                z = fmaf(sbr[i], s_sil[ln][i], z);
                z = fmaf(t, s_msk[ln][i], z);
            }
            h0[(size_t)n * HID_F + o] = z;
            hb[(size_t)n * HID_F + o] =
                __builtin_bit_cast(unsigned short, (__bf16)z);
        }
    }
}

// -------------------- CSR build: count / scan / fill -----------------------
__global__ __launch_bounds__(256) void count_kernel(
    const int* __restrict__ dst, int* __restrict__ cnt, int E)
{
    int e = blockIdx.x * 256 + threadIdx.x;
    if (e < E) atomicAdd(&cnt[dst[e]], 1);
}

__global__ __launch_bounds__(256) void scan1_kernel(
    const int* __restrict__ cnt, int* __restrict__ offs,
    int* __restrict__ bsum, int N)
{
    __shared__ int s[256];
    int base = blockIdx.x * 1024 + threadIdx.x * 4;
    int v0 = (base + 0 < N) ? cnt[base + 0] : 0;
    int v1 = (base + 1 < N) ? cnt[base + 1] : 0;
    int v2 = (base + 2 < N) ? cnt[base + 2] : 0;
    int v3 = (base + 3 < N) ? cnt[base + 3] : 0;
    int tsum = v0 + v1 + v2 + v3;
    s[threadIdx.x] = tsum;
    __syncthreads();
    for (int off = 1; off < 256; off <<= 1) {
        int t = 0;
        if (threadIdx.x >= off) t = s[threadIdx.x - off];
        __syncthreads();
        if (threadIdx.x >= off) s[threadIdx.x] += t;
        __syncthreads();
    }
    int p = s[threadIdx.x] - tsum;
    if (threadIdx.x == 255) bsum[blockIdx.x] = s[255];
    if (base + 0 < N) { offs[base + 0] = p; p += v0; }
    if (base + 1 < N) { offs[base + 1] = p; p += v1; }
    if (base + 2 < N) { offs[base + 2] = p; p += v2; }
    if (base + 3 < N) { offs[base + 3] = p; p += v3; }
}

__global__ __launch_bounds__(256) void scan2_kernel(int* __restrict__ bsum, int nblk)
{
    __shared__ int s[256];
    int v = (threadIdx.x < nblk) ? bsum[threadIdx.x] : 0;
    s[threadIdx.x] = v;
    __syncthreads();
    for (int off = 1; off < 256; off <<= 1) {
        int t = 0;
        if (threadIdx.x >= off) t = s[threadIdx.x - off];
        __syncthreads();
        if (threadIdx.x >= off) s[threadIdx.x] += t;
        __syncthreads();
    }
    if (threadIdx.x < nblk) bsum[threadIdx.x] = s[threadIdx.x] - v;
}

__global__ __launch_bounds__(256) void scan3_kernel(
    int* __restrict__ offs, const int* __restrict__ bsum, int N, int E)
{
    int i = blockIdx.x * 256 + threadIdx.x;
    if (i < N) offs[i] += bsum[i >> 10];
    if (i == 0) offs[N] = E;
}

__global__ __launch_bounds__(256) void fill_kernel(
    const int* __restrict__ src, const int* __restrict__ dst,
    const int* __restrict__ offs, int* __restrict__ cursor,
    int* __restrict__ csr, int E)
{
    int e = blockIdx.x * 256 + threadIdx.x;
    if (e >= E) return;
    int d = dst[e];
    int p = atomicAdd(&cursor[d], 1);
    csr[offs[d] + p] = src[e];
}

// ---------- gather aggregation (bf16 rows): mean over in-neighbors ---------
// one wave per node; lane l owns features [2l, 2l+1] (one dword of hb row)
__global__ __launch_bounds__(256) void agg_kernel(
    const unsigned short* __restrict__ hb, const int* __restrict__ csr,
    const int* __restrict__ offs, unsigned short* __restrict__ meanb, int N)
{
    int wid  = (blockIdx.x * 256 + threadIdx.x) >> 6;   // node id
    int lane = threadIdx.x & 63;
    if (wid >= N) return;
    int lo = offs[wid], hi = offs[wid + 1];
    float ax = 0.f, ay = 0.f;
    for (int base = lo; base < hi; base += 64) {
        int m = hi - base;
        int idx = 0;
        if (lane < m) idx = csr[base + lane];
        int cnt = m < 64 ? m : 64;
        int j = 0;
        for (; j + 3 < cnt; j += 4) {
            int s0 = __shfl(idx, j + 0);
            int s1 = __shfl(idx, j + 1);
            int s2 = __shfl(idx, j + 2);
            int s3 = __shfl(idx, j + 3);
            unsigned int v0 = *(const unsigned int*)(hb + (size_t)s0 * HID_F + lane * 2);
            unsigned int v1 = *(const unsigned int*)(hb + (size_t)s1 * HID_F + lane * 2);
            unsigned int v2 = *(const unsigned int*)(hb + (size_t)s2 * HID_F + lane * 2);
            unsigned int v3 = *(const unsigned int*)(hb + (size_t)s3 * HID_F + lane * 2);
            ax += __builtin_bit_cast(float, v0 << 16) + __builtin_bit_cast(float, v1 << 16)
                + __builtin_bit_cast(float, v2 << 16) + __builtin_bit_cast(float, v3 << 16);
            ay += __builtin_bit_cast(float, v0 & 0xffff0000u) + __builtin_bit_cast(float, v1 & 0xffff0000u)
                + __builtin_bit_cast(float, v2 & 0xffff0000u) + __builtin_bit_cast(float, v3 & 0xffff0000u);
        }
        for (; j < cnt; ++j) {
            int s0 = __shfl(idx, j);
            unsigned int v0 = *(const unsigned int*)(hb + (size_t)s0 * HID_F + lane * 2);
            ax += __builtin_bit_cast(float, v0 << 16);
            ay += __builtin_bit_cast(float, v0 & 0xffff0000u);
        }
    }
    float inv = (hi > lo) ? 1.0f / (float)(hi - lo) : 0.0f;
    unsigned short ux = __builtin_bit_cast(unsigned short, (__bf16)(ax * inv));
    unsigned short uy = __builtin_bit_cast(unsigned short, (__bf16)(ay * inv));
    *(unsigned int*)(meanb + (size_t)wid * HID_F + lane * 2) =
        (unsigned int)ux | ((unsigned int)uy << 16);
}

// -------------------- SAGE update via MFMA ---------------------------------
// z = [hb|meanb](bf16) @ wfrag(bf16, K=256) + bias + hres (fp32); leaky.
// Block = 256 threads = 4 waves; wave w owns nodes [blk*64 + w*16, +16),
// all 128 output cols.  A-fragments are raw 16B loads (no cvt).  LDS-free.
__global__ __launch_bounds__(256) void sage_mfma_kernel(
    const unsigned short* __restrict__ hb, const unsigned short* __restrict__ meanb,
    const float* __restrict__ hres, const unsigned short* __restrict__ wfrag,
    const float* __restrict__ bias, float* __restrict__ hout,
    unsigned short* __restrict__ hbout, int N)
{
    int wv = threadIdx.x >> 6;
    int l  = threadIdx.x & 63;
    int n0 = blockIdx.x * 64 + wv * 16;
    int r  = l & 15;
    int kg = l >> 4;                          // 0..3

    const uint4* rowh = (const uint4*)(hb    + (size_t)(n0 + r) * HID_F);
    const uint4* rowm = (const uint4*)(meanb + (size_t)(n0 + r) * HID_F);
    const uint4* wp   = (const uint4*)wfrag + l;

    f32x4 acc[8] = {};
#pragma unroll
    for (int ks = 0; ks < 8; ++ks) {
        uint4 av = (ks < 4) ? rowh[ks * 4 + kg] : rowm[(ks - 4) * 4 + kg];
        bf16x8 a = __builtin_bit_cast(bf16x8, av);
#pragma unroll
        for (int c = 0; c < 8; ++c) {
            uint4 w = wp[(ks * 8 + c) * 64];
            bf16x8 b = __builtin_bit_cast(bf16x8, w);
            acc[c] = __builtin_amdgcn_mfma_f32_16x16x32_bf16(a, b, acc[c], 0, 0, 0);
        }
    }

    // epilogue: D[row=(l>>4)*4+rr][col=c*16+(l&15)]
    int row0 = kg * 4;
#pragma unroll
    for (int c = 0; c < 8; ++c) {
        int col = c * 16 + r;
        float bv = bias[col];
#pragma unroll
        for (int rr = 0; rr < 4; ++rr) {
            int grow = n0 + row0 + rr;
            if (grow < N) {
                float z = acc[c][rr] + bv + hres[(size_t)grow * HID_F + col];
                z = z > 0.f ? z : 0.01f * z;
                hout[(size_t)grow * HID_F + col] = z;
                if (hbout)
                    hbout[(size_t)grow * HID_F + col] =
                        __builtin_bit_cast(unsigned short, (__bf16)z);
            }
        }
    }
}

// ------------- fused graph-mean pool + KAN readout layer 1 ------------------
__global__ __launch_bounds__(128) void pool_readout1_kernel(
    const float* __restrict__ h, const int* __restrict__ gid,
    const float* __restrict__ coefr1, const float* __restrict__ sbr1,
    const float* __restrict__ ssr1, float* __restrict__ ymid, int N)
{
    int g = blockIdx.x;
    int i = threadIdx.x;

    int lo = 0, hi = N;
    while (lo < hi) { int m = (lo + hi) >> 1; if (gid[m] < g) lo = m + 1; else hi = m; }
    int lo2 = lo, hi2 = N;
    while (lo2 < hi2) { int m = (lo2 + hi2) >> 1; if (gid[m] < g + 1) lo2 = m + 1; else hi2 = m; }

    float acc = 0.f;
    for (int n = lo; n < lo2; ++n) acc += h[(size_t)n * HID_F + i];
    float x = acc * (1.0f / fmaxf((float)(lo2 - lo), 1.0f));

    float B[NC];
    bspline11(x, B);
    float s = silu_f(x);
    const float* cp  = coefr1 + (size_t)i * (MID_F * NC);
    const float* ssp = ssr1 + (size_t)i * MID_F;
    const float* sbp = sbr1 + (size_t)i * MID_F;
    float p[MID_F];
#pragma unroll
    for (int o = 0; o < MID_F; ++o) {
        float t = 0.f;
#pragma unroll
        for (int c = 0; c < NC; ++c) t = fmaf(cp[o * NC + c], B[c], t);
        p[o] = sbp[o] * s + ssp[o] * t;
    }

#pragma unroll
    for (int off = 32; off >= 1; off >>= 1) {
#pragma unroll
        for (int o = 0; o < MID_F; ++o) p[o] += __shfl_down(p[o], off);
    }
    __shared__ float s_part[2][MID_F];
    int lane = threadIdx.x & 63, w = threadIdx.x >> 6;
    if (lane == 0) {
#pragma unroll
        for (int o = 0; o < MID_F; ++o) s_part[w][o] = p[o];
    }
    __syncthreads();
    if (threadIdx.x < MID_F)
        ymid[g * MID_F + threadIdx.x] = s_part[0][threadIdx.x] + s_part[1][threadIdx.x];
}

// -------------------- KAN readout layer 2 + sigmoid: [512,5] -> [512,1] ----
__global__ __launch_bounds__(256) void readout2_kernel(
    const float* __restrict__ ymid, const float* __restrict__ coefr2,
    const float* __restrict__ sbr2, const float* __restrict__ ssr2,
    float* __restrict__ out)
{
    int g = blockIdx.x * 256 + threadIdx.x;
    if (g >= NG) return;
    float acc = 0.f;
#pragma unroll
    for (int i = 0; i < MID_F; ++i) {
        float x = ymid[g * MID_F + i];
        float B[NC];
        bspline11(x, B);
        float t = 0.f;
#pragma unroll
        for (int c = 0; c < NC; ++c) t = fmaf(coefr2[i * NC + c], B[c], t);
        acc += sbr2[i] * silu_f(x) + ssr2[i] * t;
    }
    out[g] = 1.0f / (1.0f + expf(-acc));
}

// ---------------------------------------------------------------------------
extern "C" void kernel_launch(void* const* d_in, const int* in_sizes, int n_in,
                              void* d_out, int out_size, void* d_ws, size_t ws_size,
                              hipStream_t stream)
{
    const float* h     = (const float*)d_in[0];
    const int*   src   = (const int*)d_in[1];
    const int*   dst   = (const int*)d_in[2];
    const int*   gid   = (const int*)d_in[3];
    const float* coef1 = (const float*)d_in[4];
    const float* sb1   = (const float*)d_in[5];
    const float* ss1   = (const float*)d_in[6];
    const float* coef2 = (const float*)d_in[7];
    const float* sb2   = (const float*)d_in[8];
    const float* ss2   = (const float*)d_in[9];
    const float* Ws0   = (const float*)d_in[10];
    const float* Wn0   = (const float*)d_in[11];
    const float* b0    = (const float*)d_in[12];
    const float* Ws1   = (const float*)d_in[13];
    const float* Wn1   = (const float*)d_in[14];
    const float* b1    = (const float*)d_in[15];
    const float* coefr1= (const float*)d_in[16];
    const float* sbr1  = (const float*)d_in[17];
    const float* ssr1  = (const float*)d_in[18];
    const float* coefr2= (const float*)d_in[19];
    const float* sbr2  = (const float*)d_in[20];
    const float* ssr2  = (const float*)d_in[21];

    const int N = in_sizes[0] / IN_F;   // 100000
    const int E = in_sizes[1];          // 1600000

    // ---- workspace layout (same total footprint as round 6) ----
    float* ws   = (float*)d_ws;
    float* mid  = ws;                                   // N*5 f32
    float* h0   = mid + (size_t)N * MID_F;              // N*128 f32
    float* h1   = h0 + (size_t)N * HID_F;               // N*128 f32
    unsigned short* meanb = (unsigned short*)(h1 + (size_t)N * HID_F);  // N*128 bf16
    unsigned short* hb    = meanb + (size_t)N * HID_F;                  // N*128 bf16
    float* ymid = (float*)(hb + (size_t)N * HID_F);     // 512*5 f32
    unsigned short* wfrag0 = (unsigned short*)(ymid + NG * MID_F);  // 32768 us
    unsigned short* wfrag1 = wfrag0 + 32768;                        // 32768 us
    int*   cnt  = (int*)(wfrag1 + 32768);               // N (reused as cursor)
    int*   offs = cnt + N;                              // N+1
    int*   bsum = offs + N + 1;                         // 256
    int*   csr  = bsum + 256;                           // E

    // poly tables aliased onto meanb (dead until agg0 writes meanb):
    float* poly1 = (float*)meanb;                       // 64*14*5*4  = 17920 f32
    float* poly2 = poly1 + IN_F * NJ * MID_F * 4;       // 5*14*128*4 = 35840 f32

    const int nblk = (N + 1023) / 1024;

    // build spline polynomial tables + bf16 weight fragment tables
    build_poly1_kernel<<<(IN_F * NJ * MID_F + 255) / 256, 256, 0, stream>>>(coef1, ss1, poly1);
    build_poly2_kernel<<<(MID_F * NJ * HID_F + 255) / 256, 256, 0, stream>>>(coef2, ss2, poly2);
    build_wfrag_kernel<<<(2 * 256 * HID_F + 255) / 256, 256, 0, stream>>>(
        Ws0, Wn0, Ws1, Wn1, wfrag0, wfrag1);

    // KAN encoder
    enc1_kernel<<<(N + 255) / 256, 256, 0, stream>>>(h, poly1, sb1, mid, N);
    enc2_kernel<<<2048, 256, 0, stream>>>(mid, poly2, sb2, h0, hb, N);

    // CSR build (once; reused by both SAGE layers)
    hipMemsetAsync(cnt, 0, (size_t)N * sizeof(int), stream);
    count_kernel<<<(E + 255) / 256, 256, 0, stream>>>(dst, cnt, E);
    scan1_kernel<<<nblk, 256, 0, stream>>>(cnt, offs, bsum, N);
    scan2_kernel<<<1, 256, 0, stream>>>(bsum, nblk);
    scan3_kernel<<<(N + 255) / 256, 256, 0, stream>>>(offs, bsum, N, E);
    hipMemsetAsync(cnt, 0, (size_t)N * sizeof(int), stream);   // cnt -> cursor
    fill_kernel<<<(E + 255) / 256, 256, 0, stream>>>(src, dst, offs, cnt, csr, E);

    // SAGE layer 0: agg from hb -> meanb; GEMM; writes h1 + hb (in place)
    agg_kernel<<<(N * 64 + 255) / 256, 256, 0, stream>>>(hb, csr, offs, meanb, N);
    sage_mfma_kernel<<<(N + 63) / 64, 256, 0, stream>>>(
        hb, meanb, h0, wfrag0, b0, h1, hb, N);

    // SAGE layer 1: output bf16 shadow not needed (pool uses fp32)
    agg_kernel<<<(N * 64 + 255) / 256, 256, 0, stream>>>(hb, csr, offs, meanb, N);
    sage_mfma_kernel<<<(N + 63) / 64, 256, 0, stream>>>(
        hb, meanb, h1, wfrag1, b1, h0, (unsigned short*)nullptr, N);

    // fused pool + readout
    pool_readout1_kernel<<<NG, 128, 0, stream>>>(h0, gid, coefr1, sbr1, ssr1, ymid, N);
    readout2_kernel<<<2, 256, 0, stream>>>(ymid, coefr2, sbr2, ssr2, (float*)d_out);
}

// Round 9
// 645.800 us; speedup vs baseline: 9.8000x; 1.0412x over previous
//
#include <hip/hip_runtime.h>

// ---------------------------------------------------------------------------
// KAN-GNN forward on MI355X.  Sizes (fixed by reference): N=100000 nodes,
// E=1600000 edges, IN=64, MID=5, HID=128, OUT=1, NG=512 graphs, C=11 basis.
// Round 8 (resubmit; round-8 bench hit GPUAcquisitionTimeout): XCD-local CSR
// build.  fill's 107MB WRITE_SIZE was partial-line writeback amplification
// (4B scattered writes to one 64B line issued from all 8 non-coherent XCDs).
// count/fill now partition dst-space 8 ways and bind each range to
// blockIdx&7 (= XCD under round-robin dispatch): each csr/cnt line is
// written by exactly one XCD -> fills in L2, one writeback.
// ---------------------------------------------------------------------------

#define IN_F   64
#define MID_F  5
#define HID_F  128
#define NG     512
#define NC     11   // G_GRID + K_SPLINE = 8 + 3
#define NJ     14   // intervals of [-1.75, 1.75) at h=0.25
#define NXCD   8

typedef __attribute__((ext_vector_type(8))) __bf16 bf16x8;
typedef __attribute__((ext_vector_type(4))) float  f32x4;

// Cubic B-spline basis on uniform knots t_j = -1.75 + 0.25 j, j=0..14.
// (used by the tiny readout kernels)
__device__ __forceinline__ void bspline11(float x, float* __restrict__ B) {
    float b[14];
#pragma unroll
    for (int j = 0; j < 14; ++j) {
        float tj = -1.75f + 0.25f * j;
        b[j] = (x >= tj && x < tj + 0.25f) ? 1.0f : 0.0f;
    }
#pragma unroll
    for (int d = 1; d <= 3; ++d) {
        float inv = 1.0f / (0.25f * d);
#pragma unroll 14
        for (int j = 0; j < 14 - 3; ++j) {
            if (j < 14 - d) {
                float tj   = -1.75f + 0.25f * j;
                float tjd1 = tj + 0.25f * (d + 1);
                b[j] = ((x - tj) * b[j] + (tjd1 - x) * b[j + 1]) * inv;
            }
        }
        if (d < 3) {
#pragma unroll
            for (int j = 11; j < 14; ++j) {
                if (j < 14 - d) {
                    float tj   = -1.75f + 0.25f * j;
                    float tjd1 = tj + 0.25f * (d + 1);
                    b[j] = ((x - tj) * b[j] + (tjd1 - x) * b[j + 1]) * inv;
                }
            }
        }
    }
#pragma unroll
    for (int j = 0; j < NC; ++j) B[j] = b[j];
}

__device__ __forceinline__ float silu_f(float x) { return x / (1.0f + expf(-x)); }

// ---- build piecewise-cubic tables: poly[idx][4] = {a,b,c,d} in local u ----
__device__ __forceinline__ float4 poly_from_coefs(float c0, float c1, float c2, float c3) {
    const float s = 1.0f / 6.0f;
    float4 p;
    p.x = (-c0 + 3.f*c1 - 3.f*c2 + c3) * s;   // u^3
    p.y = ( 3.f*c0 - 6.f*c1 + 3.f*c2) * s;    // u^2
    p.z = (-3.f*c0 + 3.f*c2) * s;             // u^1
    p.w = (      c0 + 4.f*c1 + c2) * s;       // 1
    return p;
}

// poly1 layout: [i (64)][j (14)][o (5)][4]
__global__ __launch_bounds__(256) void build_poly1_kernel(
    const float* __restrict__ coef1, const float* __restrict__ ss1,
    float* __restrict__ poly1)
{
    int idx = blockIdx.x * 256 + threadIdx.x;
    if (idx >= IN_F * NJ * MID_F) return;
    int o = idx % MID_F;
    int t = idx / MID_F;
    int j = t % NJ;
    int i = t / NJ;
    float ss = ss1[i * MID_F + o];
    float c[4];
#pragma unroll
    for (int k = 0; k < 4; ++k) {
        int cc = j - 3 + k;
        c[k] = (cc >= 0 && cc <= 10) ? coef1[(i * MID_F + o) * NC + cc] * ss : 0.f;
    }
    *(float4*)(poly1 + (size_t)idx * 4) = poly_from_coefs(c[0], c[1], c[2], c[3]);
}

// poly2 layout: [i (5)][j (14)][o (128)][4]
__global__ __launch_bounds__(256) void build_poly2_kernel(
    const float* __restrict__ coef2, const float* __restrict__ ss2,
    float* __restrict__ poly2)
{
    int idx = blockIdx.x * 256 + threadIdx.x;
    if (idx >= MID_F * NJ * HID_F) return;
    int o = idx & 127;
    int t = idx >> 7;
    int j = t % NJ;
    int i = t / NJ;
    float ss = ss2[i * HID_F + o];
    float c[4];
#pragma unroll
    for (int k = 0; k < 4; ++k) {
        int cc = j - 3 + k;
        c[k] = (cc >= 0 && cc <= 10) ? coef2[(i * HID_F + o) * NC + cc] * ss : 0.f;
    }
    *(float4*)(poly2 + (size_t)idx * 4) = poly_from_coefs(c[0], c[1], c[2], c[3]);
}

// ---- repack [Ws;Wn] (K=256 x 128) into MFMA fragment order, bf16 ----------
__global__ __launch_bounds__(256) void build_wfrag_kernel(
    const float* __restrict__ Ws0, const float* __restrict__ Wn0,
    const float* __restrict__ Ws1, const float* __restrict__ Wn1,
    unsigned short* __restrict__ wfrag0, unsigned short* __restrict__ wfrag1)
{
    int t = blockIdx.x * 256 + threadIdx.x;
    if (t >= 2 * 256 * HID_F) return;
    int layer = t >> 15;
    int e = t & 32767;
    int col = e & 127;
    int k   = e >> 7;          // 0..255
    int ks  = k >> 5;
    int kin = k & 31;
    int lg  = kin >> 3;
    int j   = kin & 7;
    int c   = col >> 4;
    int li  = col & 15;
    int l   = lg * 16 + li;
    const float* Ws = layer ? Ws1 : Ws0;
    const float* Wn = layer ? Wn1 : Wn0;
    float v = (k < HID_F) ? Ws[k * HID_F + col] : Wn[(k - HID_F) * HID_F + col];
    unsigned short us = __builtin_bit_cast(unsigned short, (__bf16)v);
    unsigned short* dst = layer ? wfrag1 : wfrag0;
    dst[((ks * 8 + c) * 64 + l) * 8 + j] = us;
}

// -------------------- KAN encoder layer 1: [N,64] -> [N,5] -----------------
__global__ __launch_bounds__(256) void enc1_kernel(
    const float* __restrict__ h, const float* __restrict__ poly1,
    const float* __restrict__ sb1, float* __restrict__ mid, int N)
{
    __shared__ float s_sb[IN_F * MID_F];
    for (int idx = threadIdx.x; idx < IN_F * MID_F; idx += 256)
        s_sb[idx] = sb1[idx];
    __syncthreads();

    int n = blockIdx.x * 256 + threadIdx.x;
    if (n >= N) return;
    const float* hr = h + (size_t)n * IN_F;
    float acc[MID_F] = {0, 0, 0, 0, 0};

#pragma unroll 4
    for (int i4 = 0; i4 < IN_F; i4 += 4) {
        float4 xv = *(const float4*)(hr + i4);
        float xs[4] = {xv.x, xv.y, xv.z, xv.w};
#pragma unroll
        for (int k = 0; k < 4; ++k) {
            int i = i4 + k;
            float x = xs[k];
            float xf = (x + 1.75f) * 4.0f;
            float fj = floorf(xf);
            int j0 = (int)fj;
            j0 = j0 < 0 ? 0 : (j0 > 13 ? 13 : j0);
            float u = xf - fj;
            float msk = (x >= -1.75f && x < 1.75f) ? 1.0f : 0.0f;
            float s = silu_f(x);
            const float* pp = poly1 + ((size_t)(i * NJ + j0) * MID_F) * 4;
#pragma unroll
            for (int o = 0; o < MID_F; ++o) {
                float4 p = *(const float4*)(pp + 4 * o);
                float t = fmaf(fmaf(fmaf(p.x, u, p.y), u, p.z), u, p.w);
                acc[o] = fmaf(s_sb[i * MID_F + o], s, acc[o]);
                acc[o] = fmaf(t, msk, acc[o]);
            }
        }
    }
#pragma unroll
    for (int o = 0; o < MID_F; ++o) mid[(size_t)n * MID_F + o] = acc[o];
}

// ------------- KAN encoder layer 2: [N,5] -> [N,128] (+ bf16 shadow) -------
__global__ __launch_bounds__(256) void enc2_kernel(
    const float* __restrict__ mid, const float* __restrict__ poly2,
    const float* __restrict__ sb2, float* __restrict__ h0,
    unsigned short* __restrict__ hb, int N)
{
    __shared__ float s_u[2][MID_F], s_sil[2][MID_F], s_msk[2][MID_F];
    __shared__ int   s_j0[2][MID_F];
    int o  = threadIdx.x & 127;
    int ln = threadIdx.x >> 7;

    float sbr[MID_F];
#pragma unroll
    for (int i = 0; i < MID_F; ++i) sbr[i] = sb2[i * HID_F + o];

    int nTiles = (N + 1) / 2;
    for (int tile = blockIdx.x; tile < nTiles; tile += gridDim.x) {
        __syncthreads();
        if (threadIdx.x < 2 * MID_F) {
            int l = threadIdx.x / MID_F, i = threadIdx.x % MID_F;
            int n = tile * 2 + l;
            float x = (n < N) ? mid[(size_t)n * MID_F + i] : 0.f;
            float xf = (x + 1.75f) * 4.0f;
            float fj = floorf(xf);
            int j0 = (int)fj;
            j0 = j0 < 0 ? 0 : (j0 > 13 ? 13 : j0);
            s_j0[l][i]  = j0;
            s_u[l][i]   = xf - fj;
            s_msk[l][i] = (x >= -1.75f && x < 1.75f) ? 1.0f : 0.0f;
            s_sil[l][i] = silu_f(x);
        }
        __syncthreads();
        int n = tile * 2 + ln;
        if (n < N) {
            float z = 0.f;
#pragma unroll
            for (int i = 0; i < MID_F; ++i) {
                float4 p = *(const float4*)(poly2 +
                            ((size_t)((i * NJ + s_j0[ln][i]) * HID_F + o)) * 4);
                float u = s_u[ln][i];
                float t = fmaf(fmaf(fmaf(p.x, u, p.y), u, p.z), u, p.w);
                z = fmaf(sbr[i], s_sil[ln][i], z);
                z = fmaf(t, s_msk[ln][i], z);
            }
            h0[(size_t)n * HID_F + o] = z;
            hb[(size_t)n * HID_F + o] =
                __builtin_bit_cast(unsigned short, (__bf16)z);
        }
    }
}

// --------- CSR build, XCD-partitioned: count8 / scan / fill8 ---------------
// Partition p = blockIdx&7 handles dst in [p*psz, (p+1)*psz); under
// round-robin workgroup dispatch all its blocks land on one XCD, so cnt/csr
// cache lines are single-XCD-owned -> full-line writebacks, no cross-XCD RMW.
__global__ __launch_bounds__(256) void count8_kernel(
    const int* __restrict__ dst, int* __restrict__ cnt, int E, int psz)
{
    int part = blockIdx.x & (NXCD - 1);
    int blk  = blockIdx.x >> 3;
    int plo = part * psz, phi = plo + psz;
    int e0 = (blk * 256 + threadIdx.x) * 4;
    if (e0 >= E) return;
    if (e0 + 3 < E) {
        int4 d4 = *(const int4*)(dst + e0);
        if (d4.x >= plo && d4.x < phi) atomicAdd(&cnt[d4.x], 1);
        if (d4.y >= plo && d4.y < phi) atomicAdd(&cnt[d4.y], 1);
        if (d4.z >= plo && d4.z < phi) atomicAdd(&cnt[d4.z], 1);
        if (d4.w >= plo && d4.w < phi) atomicAdd(&cnt[d4.w], 1);
    } else {
        for (int k = 0; k < 4 && e0 + k < E; ++k) {
            int d = dst[e0 + k];
            if (d >= plo && d < phi) atomicAdd(&cnt[d], 1);
        }
    }
}

__global__ __launch_bounds__(256) void scan1_kernel(
    const int* __restrict__ cnt, int* __restrict__ offs,
    int* __restrict__ bsum, int N)
{
    __shared__ int s[256];
    int base = blockIdx.x * 1024 + threadIdx.x * 4;
    int v0 = (base + 0 < N) ? cnt[base + 0] : 0;
    int v1 = (base + 1 < N) ? cnt[base + 1] : 0;
    int v2 = (base + 2 < N) ? cnt[base + 2] : 0;
    int v3 = (base + 3 < N) ? cnt[base + 3] : 0;
    int tsum = v0 + v1 + v2 + v3;
    s[threadIdx.x] = tsum;
    __syncthreads();
    for (int off = 1; off < 256; off <<= 1) {
        int t = 0;
        if (threadIdx.x >= off) t = s[threadIdx.x - off];
        __syncthreads();
        if (threadIdx.x >= off) s[threadIdx.x] += t;
        __syncthreads();
    }
    int p = s[threadIdx.x] - tsum;
    if (threadIdx.x == 255) bsum[blockIdx.x] = s[255];
    if (base + 0 < N) { offs[base + 0] = p; p += v0; }
    if (base + 1 < N) { offs[base + 1] = p; p += v1; }
    if (base + 2 < N) { offs[base + 2] = p; p += v2; }
    if (base + 3 < N) { offs[base + 3] = p; p += v3; }
}

__global__ __launch_bounds__(256) void scan2_kernel(int* __restrict__ bsum, int nblk)
{
    __shared__ int s[256];
    int v = (threadIdx.x < nblk) ? bsum[threadIdx.x] : 0;
    s[threadIdx.x] = v;
    __syncthreads();
    for (int off = 1; off < 256; off <<= 1) {
        int t = 0;
        if (threadIdx.x >= off) t = s[threadIdx.x - off];
        __syncthreads();
        if (threadIdx.x >= off) s[threadIdx.x] += t;
        __syncthreads();
    }
    if (threadIdx.x < nblk) bsum[threadIdx.x] = s[threadIdx.x] - v;
}

__global__ __launch_bounds__(256) void scan3_kernel(
    int* __restrict__ offs, const int* __restrict__ bsum, int N, int E)
{
    int i = blockIdx.x * 256 + threadIdx.x;
    if (i < N) offs[i] += bsum[i >> 10];
    if (i == 0) offs[N] = E;
}

__global__ __launch_bounds__(256) void fill8_kernel(
    const int* __restrict__ src, const int* __restrict__ dst,
    const int* __restrict__ offs, int* __restrict__ cursor,
    int* __restrict__ csr, int E, int psz)
{
    int part = blockIdx.x & (NXCD - 1);
    int blk  = blockIdx.x >> 3;
    int plo = part * psz, phi = plo + psz;
    int e0 = (blk * 256 + threadIdx.x) * 4;
    if (e0 >= E) return;
    if (e0 + 3 < E) {
        int4 d4 = *(const int4*)(dst + e0);
        int4 s4 = *(const int4*)(src + e0);
        if (d4.x >= plo && d4.x < phi) { int p = atomicAdd(&cursor[d4.x], 1); csr[offs[d4.x] + p] = s4.x; }
        if (d4.y >= plo && d4.y < phi) { int p = atomicAdd(&cursor[d4.y], 1); csr[offs[d4.y] + p] = s4.y; }
        if (d4.z >= plo && d4.z < phi) { int p = atomicAdd(&cursor[d4.z], 1); csr[offs[d4.z] + p] = s4.z; }
        if (d4.w >= plo && d4.w < phi) { int p = atomicAdd(&cursor[d4.w], 1); csr[offs[d4.w] + p] = s4.w; }
    } else {
        for (int k = 0; k < 4 && e0 + k < E; ++k) {
            int d = dst[e0 + k];
            if (d >= plo && d < phi) {
                int p = atomicAdd(&cursor[d], 1);
                csr[offs[d] + p] = src[e0 + k];
            }
        }
    }
}

// ---------- gather aggregation (bf16 rows): mean over in-neighbors ---------
// one wave per node; lane l owns features [2l, 2l+1] (one dword of hb row)
__global__ __launch_bounds__(256) void agg_kernel(
    const unsigned short* __restrict__ hb, const int* __restrict__ csr,
    const int* __restrict__ offs, unsigned short* __restrict__ meanb, int N)
{
    int wid  = (blockIdx.x * 256 + threadIdx.x) >> 6;   // node id
    int lane = threadIdx.x & 63;
    if (wid >= N) return;
    int lo = offs[wid], hi = offs[wid + 1];
    float ax = 0.f, ay = 0.f;
    for (int base = lo; base < hi; base += 64) {
        int m = hi - base;
        int idx = 0;
        if (lane < m) idx = csr[base + lane];
        int cnt = m < 64 ? m : 64;
        int j = 0;
        for (; j + 3 < cnt; j += 4) {
            int s0 = __shfl(idx, j + 0);
            int s1 = __shfl(idx, j + 1);
            int s2 = __shfl(idx, j + 2);
            int s3 = __shfl(idx, j + 3);
            unsigned int v0 = *(const unsigned int*)(hb + (size_t)s0 * HID_F + lane * 2);
            unsigned int v1 = *(const unsigned int*)(hb + (size_t)s1 * HID_F + lane * 2);
            unsigned int v2 = *(const unsigned int*)(hb + (size_t)s2 * HID_F + lane * 2);
            unsigned int v3 = *(const unsigned int*)(hb + (size_t)s3 * HID_F + lane * 2);
            ax += __builtin_bit_cast(float, v0 << 16) + __builtin_bit_cast(float, v1 << 16)
                + __builtin_bit_cast(float, v2 << 16) + __builtin_bit_cast(float, v3 << 16);
            ay += __builtin_bit_cast(float, v0 & 0xffff0000u) + __builtin_bit_cast(float, v1 & 0xffff0000u)
                + __builtin_bit_cast(float, v2 & 0xffff0000u) + __builtin_bit_cast(float, v3 & 0xffff0000u);
        }
        for (; j < cnt; ++j) {
            int s0 = __shfl(idx, j);
            unsigned int v0 = *(const unsigned int*)(hb + (size_t)s0 * HID_F + lane * 2);
            ax += __builtin_bit_cast(float, v0 << 16);
            ay += __builtin_bit_cast(float, v0 & 0xffff0000u);
        }
    }
    float inv = (hi > lo) ? 1.0f / (float)(hi - lo) : 0.0f;
    unsigned short ux = __builtin_bit_cast(unsigned short, (__bf16)(ax * inv));
    unsigned short uy = __builtin_bit_cast(unsigned short, (__bf16)(ay * inv));
    *(unsigned int*)(meanb + (size_t)wid * HID_F + lane * 2) =
        (unsigned int)ux | ((unsigned int)uy << 16);
}

// -------------------- SAGE update via MFMA ---------------------------------
// z = [hb|meanb](bf16) @ wfrag(bf16, K=256) + bias + hres (fp32); leaky.
__global__ __launch_bounds__(256) void sage_mfma_kernel(
    const unsigned short* __restrict__ hb, const unsigned short* __restrict__ meanb,
    const float* __restrict__ hres, const unsigned short* __restrict__ wfrag,
    const float* __restrict__ bias, float* __restrict__ hout,
    unsigned short* __restrict__ hbout, int N)
{
    int wv = threadIdx.x >> 6;
    int l  = threadIdx.x & 63;
    int n0 = blockIdx.x * 64 + wv * 16;
    int r  = l & 15;
    int kg = l >> 4;                          // 0..3

    const uint4* rowh = (const uint4*)(hb    + (size_t)(n0 + r) * HID_F);
    const uint4* rowm = (const uint4*)(meanb + (size_t)(n0 + r) * HID_F);
    const uint4* wp   = (const uint4*)wfrag + l;

    f32x4 acc[8] = {};
#pragma unroll
    for (int ks = 0; ks < 8; ++ks) {
        uint4 av = (ks < 4) ? rowh[ks * 4 + kg] : rowm[(ks - 4) * 4 + kg];
        bf16x8 a = __builtin_bit_cast(bf16x8, av);
#pragma unroll
        for (int c = 0; c < 8; ++c) {
            uint4 w = wp[(ks * 8 + c) * 64];
            bf16x8 b = __builtin_bit_cast(bf16x8, w);
            acc[c] = __builtin_amdgcn_mfma_f32_16x16x32_bf16(a, b, acc[c], 0, 0, 0);
        }
    }

    // epilogue: D[row=(l>>4)*4+rr][col=c*16+(l&15)]
    int row0 = kg * 4;
#pragma unroll
    for (int c = 0; c < 8; ++c) {
        int col = c * 16 + r;
        float bv = bias[col];
#pragma unroll
        for (int rr = 0; rr < 4; ++rr) {
            int grow = n0 + row0 + rr;
            if (grow < N) {
                float z = acc[c][rr] + bv + hres[(size_t)grow * HID_F + col];
                z = z > 0.f ? z : 0.01f * z;
                hout[(size_t)grow * HID_F + col] = z;
                if (hbout)
                    hbout[(size_t)grow * HID_F + col] =
                        __builtin_bit_cast(unsigned short, (__bf16)z);
            }
        }
    }
}

// ------------- fused graph-mean pool + KAN readout layer 1 ------------------
__global__ __launch_bounds__(128) void pool_readout1_kernel(
    const float* __restrict__ h, const int* __restrict__ gid,
    const float* __restrict__ coefr1, const float* __restrict__ sbr1,
    const float* __restrict__ ssr1, float* __restrict__ ymid, int N)
{
    int g = blockIdx.x;
    int i = threadIdx.x;

    int lo = 0, hi = N;
    while (lo < hi) { int m = (lo + hi) >> 1; if (gid[m] < g) lo = m + 1; else hi = m; }
    int lo2 = lo, hi2 = N;
    while (lo2 < hi2) { int m = (lo2 + hi2) >> 1; if (gid[m] < g + 1) lo2 = m + 1; else hi2 = m; }

    float acc = 0.f;
    for (int n = lo; n < lo2; ++n) acc += h[(size_t)n * HID_F + i];
    float x = acc * (1.0f / fmaxf((float)(lo2 - lo), 1.0f));

    float B[NC];
    bspline11(x, B);
    float s = silu_f(x);
    const float* cp  = coefr1 + (size_t)i * (MID_F * NC);
    const float* ssp = ssr1 + (size_t)i * MID_F;
    const float* sbp = sbr1 + (size_t)i * MID_F;
    float p[MID_F];
#pragma unroll
    for (int o = 0; o < MID_F; ++o) {
        float t = 0.f;
#pragma unroll
        for (int c = 0; c < NC; ++c) t = fmaf(cp[o * NC + c], B[c], t);
        p[o] = sbp[o] * s + ssp[o] * t;
    }

#pragma unroll
    for (int off = 32; off >= 1; off >>= 1) {
#pragma unroll
        for (int o = 0; o < MID_F; ++o) p[o] += __shfl_down(p[o], off);
    }
    __shared__ float s_part[2][MID_F];
    int lane = threadIdx.x & 63, w = threadIdx.x >> 6;
    if (lane == 0) {
#pragma unroll
        for (int o = 0; o < MID_F; ++o) s_part[w][o] = p[o];
    }
    __syncthreads();
    if (threadIdx.x < MID_F)
        ymid[g * MID_F + threadIdx.x] = s_part[0][threadIdx.x] + s_part[1][threadIdx.x];
}

// -------------------- KAN readout layer 2 + sigmoid: [512,5] -> [512,1] ----
__global__ __launch_bounds__(256) void readout2_kernel(
    const float* __restrict__ ymid, const float* __restrict__ coefr2,
    const float* __restrict__ sbr2, const float* __restrict__ ssr2,
    float* __restrict__ out)
{
    int g = blockIdx.x * 256 + threadIdx.x;
    if (g >= NG) return;
    float acc = 0.f;
#pragma unroll
    for (int i = 0; i < MID_F; ++i) {
        float x = ymid[g * MID_F + i];
        float B[NC];
        bspline11(x, B);
        float t = 0.f;
#pragma unroll
        for (int c = 0; c < NC; ++c) t = fmaf(coefr2[i * NC + c], B[c], t);
        acc += sbr2[i] * silu_f(x) + ssr2[i] * t;
    }
    out[g] = 1.0f / (1.0f + expf(-acc));
}

// ---------------------------------------------------------------------------
extern "C" void kernel_launch(void* const* d_in, const int* in_sizes, int n_in,
                              void* d_out, int out_size, void* d_ws, size_t ws_size,
                              hipStream_t stream)
{
    const float* h     = (const float*)d_in[0];
    const int*   src   = (const int*)d_in[1];
    const int*   dst   = (const int*)d_in[2];
    const int*   gid   = (const int*)d_in[3];
    const float* coef1 = (const float*)d_in[4];
    const float* sb1   = (const float*)d_in[5];
    const float* ss1   = (const float*)d_in[6];
    const float* coef2 = (const float*)d_in[7];
    const float* sb2   = (const float*)d_in[8];
    const float* ss2   = (const float*)d_in[9];
    const float* Ws0   = (const float*)d_in[10];
    const float* Wn0   = (const float*)d_in[11];
    const float* b0    = (const float*)d_in[12];
    const float* Ws1   = (const float*)d_in[13];
    const float* Wn1   = (const float*)d_in[14];
    const float* b1    = (const float*)d_in[15];
    const float* coefr1= (const float*)d_in[16];
    const float* sbr1  = (const float*)d_in[17];
    const float* ssr1  = (const float*)d_in[18];
    const float* coefr2= (const float*)d_in[19];
    const float* sbr2  = (const float*)d_in[20];
    const float* ssr2  = (const float*)d_in[21];

    const int N = in_sizes[0] / IN_F;   // 100000
    const int E = in_sizes[1];          // 1600000

    // ---- workspace layout (same total footprint as round 7) ----
    float* ws   = (float*)d_ws;
    float* mid  = ws;                                   // N*5 f32
    float* h0   = mid + (size_t)N * MID_F;              // N*128 f32
    float* h1   = h0 + (size_t)N * HID_F;               // N*128 f32
    unsigned short* meanb = (unsigned short*)(h1 + (size_t)N * HID_F);  // N*128 bf16
    unsigned short* hb    = meanb + (size_t)N * HID_F;                  // N*128 bf16
    float* ymid = (float*)(hb + (size_t)N * HID_F);     // 512*5 f32
    unsigned short* wfrag0 = (unsigned short*)(ymid + NG * MID_F);  // 32768 us
    unsigned short* wfrag1 = wfrag0 + 32768;                        // 32768 us
    int*   cnt  = (int*)(wfrag1 + 32768);               // N (reused as cursor)
    int*   offs = cnt + N;                              // N+1
    int*   bsum = offs + N + 1;                         // 256
    int*   csr  = bsum + 256;                           // E

    // poly tables aliased onto meanb (dead until agg0 writes meanb):
    float* poly1 = (float*)meanb;                       // 64*14*5*4  = 17920 f32
    float* poly2 = poly1 + IN_F * NJ * MID_F * 4;       // 5*14*128*4 = 35840 f32

    const int nblk = (N + 1023) / 1024;
    const int psz  = (N + NXCD - 1) / NXCD;             // 12500
    const int ngrid8 = NXCD * ((E + 256 * 4 - 1) / (256 * 4));

    // build spline polynomial tables + bf16 weight fragment tables
    build_poly1_kernel<<<(IN_F * NJ * MID_F + 255) / 256, 256, 0, stream>>>(coef1, ss1, poly1);
    build_poly2_kernel<<<(MID_F * NJ * HID_F + 255) / 256, 256, 0, stream>>>(coef2, ss2, poly2);
    build_wfrag_kernel<<<(2 * 256 * HID_F + 255) / 256, 256, 0, stream>>>(
        Ws0, Wn0, Ws1, Wn1, wfrag0, wfrag1);

    // KAN encoder
    enc1_kernel<<<(N + 255) / 256, 256, 0, stream>>>(h, poly1, sb1, mid, N);
    enc2_kernel<<<2048, 256, 0, stream>>>(mid, poly2, sb2, h0, hb, N);

    // CSR build (once; reused by both SAGE layers), XCD-partitioned
    hipMemsetAsync(cnt, 0, (size_t)N * sizeof(int), stream);
    count8_kernel<<<ngrid8, 256, 0, stream>>>(dst, cnt, E, psz);
    scan1_kernel<<<nblk, 256, 0, stream>>>(cnt, offs, bsum, N);
    scan2_kernel<<<1, 256, 0, stream>>>(bsum, nblk);
    scan3_kernel<<<(N + 255) / 256, 256, 0, stream>>>(offs, bsum, N, E);
    hipMemsetAsync(cnt, 0, (size_t)N * sizeof(int), stream);   // cnt -> cursor
    fill8_kernel<<<ngrid8, 256, 0, stream>>>(src, dst, offs, cnt, csr, E, psz);

    // SAGE layer 0: agg from hb -> meanb; GEMM; writes h1 + hb (in place)
    agg_kernel<<<(N * 64 + 255) / 256, 256, 0, stream>>>(hb, csr, offs, meanb, N);
    sage_mfma_kernel<<<(N + 63) / 64, 256, 0, stream>>>(
        hb, meanb, h0, wfrag0, b0, h1, hb, N);

    // SAGE layer 1: output bf16 shadow not needed (pool uses fp32)
    agg_kernel<<<(N * 64 + 255) / 256, 256, 0, stream>>>(hb, csr, offs, meanb, N);
    sage_mfma_kernel<<<(N + 63) / 64, 256, 0, stream>>>(
        hb, meanb, h1, wfrag1, b1, h0, (unsigned short*)nullptr, N);

    // fused pool + readout
    pool_readout1_kernel<<<NG, 128, 0, stream>>>(h0, gid, coefr1, sbr1, ssr1, ymid, N);
    readout2_kernel<<<2, 256, 0, stream>>>(ymid, coefr2, sbr2, ssr2, (float*)d_out);
}

// Round 10
// 588.047 us; speedup vs baseline: 10.7625x; 1.0982x over previous
//
#include <hip/hip_runtime.h>

// ---------------------------------------------------------------------------
// KAN-GNN forward on MI355X.  Sizes (fixed by reference): N=100000 nodes,
// E=1600000 edges, IN=64, MID=5, HID=128, OUT=1, NG=512 graphs, C=11 basis.
// Round 10: widen pool_readout1 (was 75us @ 8.8% occupancy, 1024 waves,
// serial 4B loads).  512 threads/block: float4 x 16-row-parallel pooling,
// LDS combine, then the 128-thread KAN readout epilogue unchanged.
// ---------------------------------------------------------------------------

#define IN_F   64
#define MID_F  5
#define HID_F  128
#define NG     512
#define NC     11   // G_GRID + K_SPLINE = 8 + 3
#define NJ     14   // intervals of [-1.75, 1.75) at h=0.25
#define NXCD   8

typedef __attribute__((ext_vector_type(8))) __bf16 bf16x8;
typedef __attribute__((ext_vector_type(4))) float  f32x4;

// Cubic B-spline basis on uniform knots t_j = -1.75 + 0.25 j, j=0..14.
// (used by the tiny readout kernels)
__device__ __forceinline__ void bspline11(float x, float* __restrict__ B) {
    float b[14];
#pragma unroll
    for (int j = 0; j < 14; ++j) {
        float tj = -1.75f + 0.25f * j;
        b[j] = (x >= tj && x < tj + 0.25f) ? 1.0f : 0.0f;
    }
#pragma unroll
    for (int d = 1; d <= 3; ++d) {
        float inv = 1.0f / (0.25f * d);
#pragma unroll 14
        for (int j = 0; j < 14 - 3; ++j) {
            if (j < 14 - d) {
                float tj   = -1.75f + 0.25f * j;
                float tjd1 = tj + 0.25f * (d + 1);
                b[j] = ((x - tj) * b[j] + (tjd1 - x) * b[j + 1]) * inv;
            }
        }
        if (d < 3) {
#pragma unroll
            for (int j = 11; j < 14; ++j) {
                if (j < 14 - d) {
                    float tj   = -1.75f + 0.25f * j;
                    float tjd1 = tj + 0.25f * (d + 1);
                    b[j] = ((x - tj) * b[j] + (tjd1 - x) * b[j + 1]) * inv;
                }
            }
        }
    }
#pragma unroll
    for (int j = 0; j < NC; ++j) B[j] = b[j];
}

__device__ __forceinline__ float silu_f(float x) { return x / (1.0f + expf(-x)); }

// ---- build piecewise-cubic tables: poly[idx][4] = {a,b,c,d} in local u ----
__device__ __forceinline__ float4 poly_from_coefs(float c0, float c1, float c2, float c3) {
    const float s = 1.0f / 6.0f;
    float4 p;
    p.x = (-c0 + 3.f*c1 - 3.f*c2 + c3) * s;   // u^3
    p.y = ( 3.f*c0 - 6.f*c1 + 3.f*c2) * s;    // u^2
    p.z = (-3.f*c0 + 3.f*c2) * s;             // u^1
    p.w = (      c0 + 4.f*c1 + c2) * s;       // 1
    return p;
}

// poly1 layout: [i (64)][j (14)][o (5)][4]
__global__ __launch_bounds__(256) void build_poly1_kernel(
    const float* __restrict__ coef1, const float* __restrict__ ss1,
    float* __restrict__ poly1)
{
    int idx = blockIdx.x * 256 + threadIdx.x;
    if (idx >= IN_F * NJ * MID_F) return;
    int o = idx % MID_F;
    int t = idx / MID_F;
    int j = t % NJ;
    int i = t / NJ;
    float ss = ss1[i * MID_F + o];
    float c[4];
#pragma unroll
    for (int k = 0; k < 4; ++k) {
        int cc = j - 3 + k;
        c[k] = (cc >= 0 && cc <= 10) ? coef1[(i * MID_F + o) * NC + cc] * ss : 0.f;
    }
    *(float4*)(poly1 + (size_t)idx * 4) = poly_from_coefs(c[0], c[1], c[2], c[3]);
}

// poly2 layout: [i (5)][j (14)][o (128)][4]
__global__ __launch_bounds__(256) void build_poly2_kernel(
    const float* __restrict__ coef2, const float* __restrict__ ss2,
    float* __restrict__ poly2)
{
    int idx = blockIdx.x * 256 + threadIdx.x;
    if (idx >= MID_F * NJ * HID_F) return;
    int o = idx & 127;
    int t = idx >> 7;
    int j = t % NJ;
    int i = t / NJ;
    float ss = ss2[i * HID_F + o];
    float c[4];
#pragma unroll
    for (int k = 0; k < 4; ++k) {
        int cc = j - 3 + k;
        c[k] = (cc >= 0 && cc <= 10) ? coef2[(i * HID_F + o) * NC + cc] * ss : 0.f;
    }
    *(float4*)(poly2 + (size_t)idx * 4) = poly_from_coefs(c[0], c[1], c[2], c[3]);
}

// ---- repack [Ws;Wn] (K=256 x 128) into MFMA fragment order, bf16 ----------
__global__ __launch_bounds__(256) void build_wfrag_kernel(
    const float* __restrict__ Ws0, const float* __restrict__ Wn0,
    const float* __restrict__ Ws1, const float* __restrict__ Wn1,
    unsigned short* __restrict__ wfrag0, unsigned short* __restrict__ wfrag1)
{
    int t = blockIdx.x * 256 + threadIdx.x;
    if (t >= 2 * 256 * HID_F) return;
    int layer = t >> 15;
    int e = t & 32767;
    int col = e & 127;
    int k   = e >> 7;          // 0..255
    int ks  = k >> 5;
    int kin = k & 31;
    int lg  = kin >> 3;
    int j   = kin & 7;
    int c   = col >> 4;
    int li  = col & 15;
    int l   = lg * 16 + li;
    const float* Ws = layer ? Ws1 : Ws0;
    const float* Wn = layer ? Wn1 : Wn0;
    float v = (k < HID_F) ? Ws[k * HID_F + col] : Wn[(k - HID_F) * HID_F + col];
    unsigned short us = __builtin_bit_cast(unsigned short, (__bf16)v);
    unsigned short* dst = layer ? wfrag1 : wfrag0;
    dst[((ks * 8 + c) * 64 + l) * 8 + j] = us;
}

// -------------------- KAN encoder layer 1: [N,64] -> [N,5] -----------------
__global__ __launch_bounds__(256) void enc1_kernel(
    const float* __restrict__ h, const float* __restrict__ poly1,
    const float* __restrict__ sb1, float* __restrict__ mid, int N)
{
    __shared__ float s_sb[IN_F * MID_F];
    for (int idx = threadIdx.x; idx < IN_F * MID_F; idx += 256)
        s_sb[idx] = sb1[idx];
    __syncthreads();

    int n = blockIdx.x * 256 + threadIdx.x;
    if (n >= N) return;
    const float* hr = h + (size_t)n * IN_F;
    float acc[MID_F] = {0, 0, 0, 0, 0};

#pragma unroll 4
    for (int i4 = 0; i4 < IN_F; i4 += 4) {
        float4 xv = *(const float4*)(hr + i4);
        float xs[4] = {xv.x, xv.y, xv.z, xv.w};
#pragma unroll
        for (int k = 0; k < 4; ++k) {
            int i = i4 + k;
            float x = xs[k];
            float xf = (x + 1.75f) * 4.0f;
            float fj = floorf(xf);
            int j0 = (int)fj;
            j0 = j0 < 0 ? 0 : (j0 > 13 ? 13 : j0);
            float u = xf - fj;
            float msk = (x >= -1.75f && x < 1.75f) ? 1.0f : 0.0f;
            float s = silu_f(x);
            const float* pp = poly1 + ((size_t)(i * NJ + j0) * MID_F) * 4;
#pragma unroll
            for (int o = 0; o < MID_F; ++o) {
                float4 p = *(const float4*)(pp + 4 * o);
                float t = fmaf(fmaf(fmaf(p.x, u, p.y), u, p.z), u, p.w);
                acc[o] = fmaf(s_sb[i * MID_F + o], s, acc[o]);
                acc[o] = fmaf(t, msk, acc[o]);
            }
        }
    }
#pragma unroll
    for (int o = 0; o < MID_F; ++o) mid[(size_t)n * MID_F + o] = acc[o];
}

// ------------- KAN encoder layer 2: [N,5] -> [N,128] (+ bf16 shadow) -------
__global__ __launch_bounds__(256) void enc2_kernel(
    const float* __restrict__ mid, const float* __restrict__ poly2,
    const float* __restrict__ sb2, float* __restrict__ h0,
    unsigned short* __restrict__ hb, int N)
{
    __shared__ float s_u[2][MID_F], s_sil[2][MID_F], s_msk[2][MID_F];
    __shared__ int   s_j0[2][MID_F];
    int o  = threadIdx.x & 127;
    int ln = threadIdx.x >> 7;

    float sbr[MID_F];
#pragma unroll
    for (int i = 0; i < MID_F; ++i) sbr[i] = sb2[i * HID_F + o];

    int nTiles = (N + 1) / 2;
    for (int tile = blockIdx.x; tile < nTiles; tile += gridDim.x) {
        __syncthreads();
        if (threadIdx.x < 2 * MID_F) {
            int l = threadIdx.x / MID_F, i = threadIdx.x % MID_F;
            int n = tile * 2 + l;
            float x = (n < N) ? mid[(size_t)n * MID_F + i] : 0.f;
            float xf = (x + 1.75f) * 4.0f;
            float fj = floorf(xf);
            int j0 = (int)fj;
            j0 = j0 < 0 ? 0 : (j0 > 13 ? 13 : j0);
            s_j0[l][i]  = j0;
            s_u[l][i]   = xf - fj;
            s_msk[l][i] = (x >= -1.75f && x < 1.75f) ? 1.0f : 0.0f;
            s_sil[l][i] = silu_f(x);
        }
        __syncthreads();
        int n = tile * 2 + ln;
        if (n < N) {
            float z = 0.f;
#pragma unroll
            for (int i = 0; i < MID_F; ++i) {
                float4 p = *(const float4*)(poly2 +
                            ((size_t)((i * NJ + s_j0[ln][i]) * HID_F + o)) * 4);
                float u = s_u[ln][i];
                float t = fmaf(fmaf(fmaf(p.x, u, p.y), u, p.z), u, p.w);
                z = fmaf(sbr[i], s_sil[ln][i], z);
                z = fmaf(t, s_msk[ln][i], z);
            }
            h0[(size_t)n * HID_F + o] = z;
            hb[(size_t)n * HID_F + o] =
                __builtin_bit_cast(unsigned short, (__bf16)z);
        }
    }
}

// --------- CSR build, XCD-partitioned: count8 / scan / fill8 ---------------
__global__ __launch_bounds__(256) void count8_kernel(
    const int* __restrict__ dst, int* __restrict__ cnt, int E, int psz)
{
    int part = blockIdx.x & (NXCD - 1);
    int blk  = blockIdx.x >> 3;
    int plo = part * psz, phi = plo + psz;
    int e0 = (blk * 256 + threadIdx.x) * 4;
    if (e0 >= E) return;
    if (e0 + 3 < E) {
        int4 d4 = *(const int4*)(dst + e0);
        if (d4.x >= plo && d4.x < phi) atomicAdd(&cnt[d4.x], 1);
        if (d4.y >= plo && d4.y < phi) atomicAdd(&cnt[d4.y], 1);
        if (d4.z >= plo && d4.z < phi) atomicAdd(&cnt[d4.z], 1);
        if (d4.w >= plo && d4.w < phi) atomicAdd(&cnt[d4.w], 1);
    } else {
        for (int k = 0; k < 4 && e0 + k < E; ++k) {
            int d = dst[e0 + k];
            if (d >= plo && d < phi) atomicAdd(&cnt[d], 1);
        }
    }
}

__global__ __launch_bounds__(256) void scan1_kernel(
    const int* __restrict__ cnt, int* __restrict__ offs,
    int* __restrict__ bsum, int N)
{
    __shared__ int s[256];
    int base = blockIdx.x * 1024 + threadIdx.x * 4;
    int v0 = (base + 0 < N) ? cnt[base + 0] : 0;
    int v1 = (base + 1 < N) ? cnt[base + 1] : 0;
    int v2 = (base + 2 < N) ? cnt[base + 2] : 0;
    int v3 = (base + 3 < N) ? cnt[base + 3] : 0;
    int tsum = v0 + v1 + v2 + v3;
    s[threadIdx.x] = tsum;
    __syncthreads();
    for (int off = 1; off < 256; off <<= 1) {
        int t = 0;
        if (threadIdx.x >= off) t = s[threadIdx.x - off];
        __syncthreads();
        if (threadIdx.x >= off) s[threadIdx.x] += t;
        __syncthreads();
    }
    int p = s[threadIdx.x] - tsum;
    if (threadIdx.x == 255) bsum[blockIdx.x] = s[255];
    if (base + 0 < N) { offs[base + 0] = p; p += v0; }
    if (base + 1 < N) { offs[base + 1] = p; p += v1; }
    if (base + 2 < N) { offs[base + 2] = p; p += v2; }
    if (base + 3 < N) { offs[base + 3] = p; p += v3; }
}

__global__ __launch_bounds__(256) void scan2_kernel(int* __restrict__ bsum, int nblk)
{
    __shared__ int s[256];
    int v = (threadIdx.x < nblk) ? bsum[threadIdx.x] : 0;
    s[threadIdx.x] = v;
    __syncthreads();
    for (int off = 1; off < 256; off <<= 1) {
        int t = 0;
        if (threadIdx.x >= off) t = s[threadIdx.x - off];
        __syncthreads();
        if (threadIdx.x >= off) s[threadIdx.x] += t;
        __syncthreads();
    }
    if (threadIdx.x < nblk) bsum[threadIdx.x] = s[threadIdx.x] - v;
}

__global__ __launch_bounds__(256) void scan3_kernel(
    int* __restrict__ offs, const int* __restrict__ bsum, int N, int E)
{
    int i = blockIdx.x * 256 + threadIdx.x;
    if (i < N) offs[i] += bsum[i >> 10];
    if (i == 0) offs[N] = E;
}

__global__ __launch_bounds__(256) void fill8_kernel(
    const int* __restrict__ src, const int* __restrict__ dst,
    const int* __restrict__ offs, int* __restrict__ cursor,
    int* __restrict__ csr, int E, int psz)
{
    int part = blockIdx.x & (NXCD - 1);
    int blk  = blockIdx.x >> 3;
    int plo = part * psz, phi = plo + psz;
    int e0 = (blk * 256 + threadIdx.x) * 4;
    if (e0 >= E) return;
    if (e0 + 3 < E) {
        int4 d4 = *(const int4*)(dst + e0);
        int4 s4 = *(const int4*)(src + e0);
        if (d4.x >= plo && d4.x < phi) { int p = atomicAdd(&cursor[d4.x], 1); csr[offs[d4.x] + p] = s4.x; }
        if (d4.y >= plo && d4.y < phi) { int p = atomicAdd(&cursor[d4.y], 1); csr[offs[d4.y] + p] = s4.y; }
        if (d4.z >= plo && d4.z < phi) { int p = atomicAdd(&cursor[d4.z], 1); csr[offs[d4.z] + p] = s4.z; }
        if (d4.w >= plo && d4.w < phi) { int p = atomicAdd(&cursor[d4.w], 1); csr[offs[d4.w] + p] = s4.w; }
    } else {
        for (int k = 0; k < 4 && e0 + k < E; ++k) {
            int d = dst[e0 + k];
            if (d >= plo && d < phi) {
                int p = atomicAdd(&cursor[d], 1);
                csr[offs[d] + p] = src[e0 + k];
            }
        }
    }
}

// ---------- gather aggregation (bf16 rows): mean over in-neighbors ---------
// one wave per node; lane l owns features [2l, 2l+1] (one dword of hb row)
__global__ __launch_bounds__(256) void agg_kernel(
    const unsigned short* __restrict__ hb, const int* __restrict__ csr,
    const int* __restrict__ offs, unsigned short* __restrict__ meanb, int N)
{
    int wid  = (blockIdx.x * 256 + threadIdx.x) >> 6;   // node id
    int lane = threadIdx.x & 63;
    if (wid >= N) return;
    int lo = offs[wid], hi = offs[wid + 1];
    float ax = 0.f, ay = 0.f;
    for (int base = lo; base < hi; base += 64) {
        int m = hi - base;
        int idx = 0;
        if (lane < m) idx = csr[base + lane];
        int cnt = m < 64 ? m : 64;
        int j = 0;
        for (; j + 3 < cnt; j += 4) {
            int s0 = __shfl(idx, j + 0);
            int s1 = __shfl(idx, j + 1);
            int s2 = __shfl(idx, j + 2);
            int s3 = __shfl(idx, j + 3);
            unsigned int v0 = *(const unsigned int*)(hb + (size_t)s0 * HID_F + lane * 2);
            unsigned int v1 = *(const unsigned int*)(hb + (size_t)s1 * HID_F + lane * 2);
            unsigned int v2 = *(const unsigned int*)(hb + (size_t)s2 * HID_F + lane * 2);
            unsigned int v3 = *(const unsigned int*)(hb + (size_t)s3 * HID_F + lane * 2);
            ax += __builtin_bit_cast(float, v0 << 16) + __builtin_bit_cast(float, v1 << 16)
                + __builtin_bit_cast(float, v2 << 16) + __builtin_bit_cast(float, v3 << 16);
            ay += __builtin_bit_cast(float, v0 & 0xffff0000u) + __builtin_bit_cast(float, v1 & 0xffff0000u)
                + __builtin_bit_cast(float, v2 & 0xffff0000u) + __builtin_bit_cast(float, v3 & 0xffff0000u);
        }
        for (; j < cnt; ++j) {
            int s0 = __shfl(idx, j);
            unsigned int v0 = *(const unsigned int*)(hb + (size_t)s0 * HID_F + lane * 2);
            ax += __builtin_bit_cast(float, v0 << 16);
            ay += __builtin_bit_cast(float, v0 & 0xffff0000u);
        }
    }
    float inv = (hi > lo) ? 1.0f / (float)(hi - lo) : 0.0f;
    unsigned short ux = __builtin_bit_cast(unsigned short, (__bf16)(ax * inv));
    unsigned short uy = __builtin_bit_cast(unsigned short, (__bf16)(ay * inv));
    *(unsigned int*)(meanb + (size_t)wid * HID_F + lane * 2) =
        (unsigned int)ux | ((unsigned int)uy << 16);
}

// -------------------- SAGE update via MFMA ---------------------------------
// z = [hb|meanb](bf16) @ wfrag(bf16, K=256) + bias + hres (fp32); leaky.
__global__ __launch_bounds__(256) void sage_mfma_kernel(
    const unsigned short* __restrict__ hb, const unsigned short* __restrict__ meanb,
    const float* __restrict__ hres, const unsigned short* __restrict__ wfrag,
    const float* __restrict__ bias, float* __restrict__ hout,
    unsigned short* __restrict__ hbout, int N)
{
    int wv = threadIdx.x >> 6;
    int l  = threadIdx.x & 63;
    int n0 = blockIdx.x * 64 + wv * 16;
    int r  = l & 15;
    int kg = l >> 4;                          // 0..3

    const uint4* rowh = (const uint4*)(hb    + (size_t)(n0 + r) * HID_F);
    const uint4* rowm = (const uint4*)(meanb + (size_t)(n0 + r) * HID_F);
    const uint4* wp   = (const uint4*)wfrag + l;

    f32x4 acc[8] = {};
#pragma unroll
    for (int ks = 0; ks < 8; ++ks) {
        uint4 av = (ks < 4) ? rowh[ks * 4 + kg] : rowm[(ks - 4) * 4 + kg];
        bf16x8 a = __builtin_bit_cast(bf16x8, av);
#pragma unroll
        for (int c = 0; c < 8; ++c) {
            uint4 w = wp[(ks * 8 + c) * 64];
            bf16x8 b = __builtin_bit_cast(bf16x8, w);
            acc[c] = __builtin_amdgcn_mfma_f32_16x16x32_bf16(a, b, acc[c], 0, 0, 0);
        }
    }

    // epilogue: D[row=(l>>4)*4+rr][col=c*16+(l&15)]
    int row0 = kg * 4;
#pragma unroll
    for (int c = 0; c < 8; ++c) {
        int col = c * 16 + r;
        float bv = bias[col];
#pragma unroll
        for (int rr = 0; rr < 4; ++rr) {
            int grow = n0 + row0 + rr;
            if (grow < N) {
                float z = acc[c][rr] + bv + hres[(size_t)grow * HID_F + col];
                z = z > 0.f ? z : 0.01f * z;
                hout[(size_t)grow * HID_F + col] = z;
                if (hbout)
                    hbout[(size_t)grow * HID_F + col] =
                        __builtin_bit_cast(unsigned short, (__bf16)z);
            }
        }
    }
}

// ------------- fused graph-mean pool + KAN readout layer 1 ------------------
// 512 threads: 16-row x float4 parallel pooling -> LDS combine -> 128-thread
// KAN epilogue (thread i owns pooled feature i).
__global__ __launch_bounds__(512) void pool_readout1_kernel(
    const float* __restrict__ h, const int* __restrict__ gid,
    const float* __restrict__ coefr1, const float* __restrict__ sbr1,
    const float* __restrict__ ssr1, float* __restrict__ ymid, int N)
{
    int g = blockIdx.x;
    int tid = threadIdx.x;
    __shared__ int s_lo, s_hi;
    if (tid == 0) {
        int lo = 0, hi = N;
        while (lo < hi) { int m = (lo + hi) >> 1; if (gid[m] < g) lo = m + 1; else hi = m; }
        s_lo = lo;
        int lo2 = lo, hi2 = N;
        while (lo2 < hi2) { int m = (lo2 + hi2) >> 1; if (gid[m] < g + 1) lo2 = m + 1; else hi2 = m; }
        s_hi = lo2;
    }
    __syncthreads();
    int lo = s_lo, hi = s_hi;

    // parallel pooling: row-group ro = tid>>5 (16 rows in flight), cols c4..c4+3
    int ro = tid >> 5;
    int c4 = (tid & 31) * 4;
    float4 a = {0.f, 0.f, 0.f, 0.f};
    for (int n = lo + ro; n < hi; n += 16) {
        float4 v = *(const float4*)(h + (size_t)n * HID_F + c4);
        a.x += v.x; a.y += v.y; a.z += v.z; a.w += v.w;
    }
    __shared__ float s_acc[16][HID_F];   // 8 KB
    *(float4*)(&s_acc[ro][c4]) = a;
    __syncthreads();

    // KAN epilogue on first 128 threads (thread i owns feature i)
    __shared__ float s_part[2][MID_F];
    float p[MID_F];
    int i = tid;
    if (tid < HID_F) {
        float acc = 0.f;
#pragma unroll
        for (int r = 0; r < 16; ++r) acc += s_acc[r][i];
        float x = acc * (1.0f / fmaxf((float)(hi - lo), 1.0f));

        float B[NC];
        bspline11(x, B);
        float s = silu_f(x);
        const float* cp  = coefr1 + (size_t)i * (MID_F * NC);
        const float* ssp = ssr1 + (size_t)i * MID_F;
        const float* sbp = sbr1 + (size_t)i * MID_F;
#pragma unroll
        for (int o = 0; o < MID_F; ++o) {
            float t = 0.f;
#pragma unroll
            for (int c = 0; c < NC; ++c) t = fmaf(cp[o * NC + c], B[c], t);
            p[o] = sbp[o] * s + ssp[o] * t;
        }
#pragma unroll
        for (int off = 32; off >= 1; off >>= 1) {
#pragma unroll
            for (int o = 0; o < MID_F; ++o) p[o] += __shfl_down(p[o], off);
        }
        int lane = tid & 63, w = tid >> 6;
        if (lane == 0) {
#pragma unroll
            for (int o = 0; o < MID_F; ++o) s_part[w][o] = p[o];
        }
    }
    __syncthreads();
    if (tid < MID_F)
        ymid[g * MID_F + tid] = s_part[0][tid] + s_part[1][tid];
}

// -------------------- KAN readout layer 2 + sigmoid: [512,5] -> [512,1] ----
__global__ __launch_bounds__(256) void readout2_kernel(
    const float* __restrict__ ymid, const float* __restrict__ coefr2,
    const float* __restrict__ sbr2, const float* __restrict__ ssr2,
    float* __restrict__ out)
{
    int g = blockIdx.x * 256 + threadIdx.x;
    if (g >= NG) return;
    float acc = 0.f;
#pragma unroll
    for (int i = 0; i < MID_F; ++i) {
        float x = ymid[g * MID_F + i];
        float B[NC];
        bspline11(x, B);
        float t = 0.f;
#pragma unroll
        for (int c = 0; c < NC; ++c) t = fmaf(coefr2[i * NC + c], B[c], t);
        acc += sbr2[i] * silu_f(x) + ssr2[i] * t;
    }
    out[g] = 1.0f / (1.0f + expf(-acc));
}

// ---------------------------------------------------------------------------
extern "C" void kernel_launch(void* const* d_in, const int* in_sizes, int n_in,
                              void* d_out, int out_size, void* d_ws, size_t ws_size,
                              hipStream_t stream)
{
    const float* h     = (const float*)d_in[0];
    const int*   src   = (const int*)d_in[1];
    const int*   dst   = (const int*)d_in[2];
    const int*   gid   = (const int*)d_in[3];
    const float* coef1 = (const float*)d_in[4];
    const float* sb1   = (const float*)d_in[5];
    const float* ss1   = (const float*)d_in[6];
    const float* coef2 = (const float*)d_in[7];
    const float* sb2   = (const float*)d_in[8];
    const float* ss2   = (const float*)d_in[9];
    const float* Ws0   = (const float*)d_in[10];
    const float* Wn0   = (const float*)d_in[11];
    const float* b0    = (const float*)d_in[12];
    const float* Ws1   = (const float*)d_in[13];
    const float* Wn1   = (const float*)d_in[14];
    const float* b1    = (const float*)d_in[15];
    const float* coefr1= (const float*)d_in[16];
    const float* sbr1  = (const float*)d_in[17];
    const float* ssr1  = (const float*)d_in[18];
    const float* coefr2= (const float*)d_in[19];
    const float* sbr2  = (const float*)d_in[20];
    const float* ssr2  = (const float*)d_in[21];

    const int N = in_sizes[0] / IN_F;   // 100000
    const int E = in_sizes[1];          // 1600000

    // ---- workspace layout (same total footprint as round 8) ----
    float* ws   = (float*)d_ws;
    float* mid  = ws;                                   // N*5 f32
    float* h0   = mid + (size_t)N * MID_F;              // N*128 f32
    float* h1   = h0 + (size_t)N * HID_F;               // N*128 f32
    unsigned short* meanb = (unsigned short*)(h1 + (size_t)N * HID_F);  // N*128 bf16
    unsigned short* hb    = meanb + (size_t)N * HID_F;                  // N*128 bf16
    float* ymid = (float*)(hb + (size_t)N * HID_F);     // 512*5 f32
    unsigned short* wfrag0 = (unsigned short*)(ymid + NG * MID_F);  // 32768 us
    unsigned short* wfrag1 = wfrag0 + 32768;                        // 32768 us
    int*   cnt  = (int*)(wfrag1 + 32768);               // N (reused as cursor)
    int*   offs = cnt + N;                              // N+1
    int*   bsum = offs + N + 1;                         // 256
    int*   csr  = bsum + 256;                           // E

    // poly tables aliased onto meanb (dead until agg0 writes meanb):
    float* poly1 = (float*)meanb;                       // 64*14*5*4  = 17920 f32
    float* poly2 = poly1 + IN_F * NJ * MID_F * 4;       // 5*14*128*4 = 35840 f32

    const int nblk = (N + 1023) / 1024;
    const int psz  = (N + NXCD - 1) / NXCD;             // 12500
    const int ngrid8 = NXCD * ((E + 256 * 4 - 1) / (256 * 4));

    // build spline polynomial tables + bf16 weight fragment tables
    build_poly1_kernel<<<(IN_F * NJ * MID_F + 255) / 256, 256, 0, stream>>>(coef1, ss1, poly1);
    build_poly2_kernel<<<(MID_F * NJ * HID_F + 255) / 256, 256, 0, stream>>>(coef2, ss2, poly2);
    build_wfrag_kernel<<<(2 * 256 * HID_F + 255) / 256, 256, 0, stream>>>(
        Ws0, Wn0, Ws1, Wn1, wfrag0, wfrag1);

    // KAN encoder
    enc1_kernel<<<(N + 255) / 256, 256, 0, stream>>>(h, poly1, sb1, mid, N);
    enc2_kernel<<<2048, 256, 0, stream>>>(mid, poly2, sb2, h0, hb, N);

    // CSR build (once; reused by both SAGE layers), XCD-partitioned
    hipMemsetAsync(cnt, 0, (size_t)N * sizeof(int), stream);
    count8_kernel<<<ngrid8, 256, 0, stream>>>(dst, cnt, E, psz);
    scan1_kernel<<<nblk, 256, 0, stream>>>(cnt, offs, bsum, N);
    scan2_kernel<<<1, 256, 0, stream>>>(bsum, nblk);
    scan3_kernel<<<(N + 255) / 256, 256, 0, stream>>>(offs, bsum, N, E);
    hipMemsetAsync(cnt, 0, (size_t)N * sizeof(int), stream);   // cnt -> cursor
    fill8_kernel<<<ngrid8, 256, 0, stream>>>(src, dst, offs, cnt, csr, E, psz);

    // SAGE layer 0: agg from hb -> meanb; GEMM; writes h1 + hb (in place)
    agg_kernel<<<(N * 64 + 255) / 256, 256, 0, stream>>>(hb, csr, offs, meanb, N);
    sage_mfma_kernel<<<(N + 63) / 64, 256, 0, stream>>>(
        hb, meanb, h0, wfrag0, b0, h1, hb, N);

    // SAGE layer 1: output bf16 shadow not needed (pool uses fp32)
    agg_kernel<<<(N * 64 + 255) / 256, 256, 0, stream>>>(hb, csr, offs, meanb, N);
    sage_mfma_kernel<<<(N + 63) / 64, 256, 0, stream>>>(
        hb, meanb, h1, wfrag1, b1, h0, (unsigned short*)nullptr, N);

    // fused pool + readout
    pool_readout1_kernel<<<NG, 512, 0, stream>>>(h0, gid, coefr1, sbr1, ssr1, ymid, N);
    readout2_kernel<<<2, 256, 0, stream>>>(ymid, coefr2, sbr2, ssr2, (float*)d_out);
}